// Round 1
// baseline (380.385 us; speedup 1.0000x reference)
//
#include <hip/hip_runtime.h>

// Problem constants: B=4, T=2048, D=1024, P=128
#define BB 4
#define TT 2048
#define DD 1024
#define PP 128
#define NC 16      // chunks per batch (T / 128)
#define CH 128     // chunk length

// ---------------------------------------------------------------------------
// Generic fp32 tiled GEMM: C[M,N] = A[M,K] @ B[K,N] (+ bias[N])
// 64x64 tile, BK=16, 256 threads, 4x4 per thread.
// ---------------------------------------------------------------------------
#define BM 64
#define BN 64
#define BK 16

__global__ __launch_bounds__(256) void gemm_bias(
    const float* __restrict__ A, const float* __restrict__ B,
    const float* __restrict__ bias, float* __restrict__ C,
    int M, int N, int K) {
  __shared__ float As[BK][BM + 1];
  __shared__ float Bs[BK][BN + 1];
  const int tid = threadIdx.x;
  const int tx = tid & 15;        // col group (4 cols)
  const int ty = tid >> 4;        // row group (4 rows)
  const int bm = blockIdx.y * BM;
  const int bn = blockIdx.x * BN;
  float acc[4][4] = {};
  for (int k0 = 0; k0 < K; k0 += BK) {
#pragma unroll
    for (int i = 0; i < (BM * BK) / 256; ++i) {
      int idx = tid + i * 256;
      int m = idx >> 4, k = idx & 15;                 // A tile stored transposed
      As[k][m] = A[(size_t)(bm + m) * K + k0 + k];
    }
#pragma unroll
    for (int i = 0; i < (BK * BN) / 256; ++i) {
      int idx = tid + i * 256;
      int k = idx >> 6, n = idx & 63;
      Bs[k][n] = B[(size_t)(k0 + k) * N + bn + n];
    }
    __syncthreads();
#pragma unroll
    for (int k = 0; k < BK; ++k) {
      float a[4], bv[4];
#pragma unroll
      for (int i = 0; i < 4; ++i) a[i] = As[k][ty * 4 + i];
#pragma unroll
      for (int j = 0; j < 4; ++j) bv[j] = Bs[k][tx * 4 + j];
#pragma unroll
      for (int i = 0; i < 4; ++i)
#pragma unroll
        for (int j = 0; j < 4; ++j) acc[i][j] += a[i] * bv[j];
    }
    __syncthreads();
  }
#pragma unroll
  for (int i = 0; i < 4; ++i) {
    int m = bm + ty * 4 + i;
#pragma unroll
    for (int j = 0; j < 4; ++j) {
      int n = bn + tx * 4 + j;
      C[(size_t)m * N + n] = acc[i][j] + (bias ? bias[n] : 0.f);
    }
  }
}

// ---------------------------------------------------------------------------
// Per-chunk state: Sc[b,c,i,j] = sum_{s in chunk} decay[c*128+s]*V[s,i]*K[s,j]
// grid (2,2,B*NC): each block computes a 64x64 tile of the 128x128 state.
// ---------------------------------------------------------------------------
__global__ __launch_bounds__(256) void chunk_state(
    const float* __restrict__ V, const float* __restrict__ Km,
    const float* __restrict__ decay, float* __restrict__ Sc) {
  const int bi = blockIdx.x, bj = blockIdx.y, bc = blockIdx.z;
  const int b = bc >> 4, c = bc & 15;
  const float* Vc = V + ((size_t)(b * TT + c * CH)) * PP;
  const float* Kc = Km + ((size_t)(b * TT + c * CH)) * PP;
  const float* dc = decay + c * CH;
  __shared__ float As[16][65];
  __shared__ float Bs[16][65];
  const int tid = threadIdx.x;
  const int tx = tid & 15, ty = tid >> 4;
  float acc[4][4] = {};
  for (int s0 = 0; s0 < CH; s0 += 16) {
#pragma unroll
    for (int i = 0; i < 4; ++i) {
      int idx = tid + i * 256;
      int k = idx >> 6, m = idx & 63;
      As[k][m] = dc[s0 + k] * Vc[(size_t)(s0 + k) * PP + bi * 64 + m];
      Bs[k][m] = Kc[(size_t)(s0 + k) * PP + bj * 64 + m];
    }
    __syncthreads();
#pragma unroll
    for (int k = 0; k < 16; ++k) {
      float a[4], bv[4];
#pragma unroll
      for (int i = 0; i < 4; ++i) a[i] = As[k][ty * 4 + i];
#pragma unroll
      for (int j = 0; j < 4; ++j) bv[j] = Bs[k][tx * 4 + j];
#pragma unroll
      for (int i = 0; i < 4; ++i)
#pragma unroll
        for (int j = 0; j < 4; ++j) acc[i][j] += a[i] * bv[j];
    }
    __syncthreads();
  }
#pragma unroll
  for (int i = 0; i < 4; ++i) {
    int ii = bi * 64 + ty * 4 + i;
#pragma unroll
    for (int j = 0; j < 4; ++j) {
      int jj = bj * 64 + tx * 4 + j;
      Sc[((size_t)bc * PP + ii) * PP + jj] = acc[i][j];
    }
  }
}

// ---------------------------------------------------------------------------
// Exclusive prefix scan over chunks (per batch, per element of 128x128 state)
// grid (64, B), 256 threads: element-parallel serial scan over 16 chunks.
// ---------------------------------------------------------------------------
__global__ __launch_bounds__(256) void chunk_scan(
    const float* __restrict__ Sc, float* __restrict__ Sx) {
  const int b = blockIdx.y;
  const int e = blockIdx.x * 256 + threadIdx.x;  // < 128*128
  float run = 0.f;
#pragma unroll
  for (int c = 0; c < NC; ++c) {
    size_t idx = ((size_t)(b * NC + c)) * (PP * PP) + e;
    Sx[idx] = run;
    run += Sc[idx];
  }
}

// ---------------------------------------------------------------------------
// Attention core per (b, chunk): Y = tril(Q V^T ⊙ decay) K + Q @ S_excl
// 512 threads; each thread computes an 8x4 tile of the 128x128 chunk output.
// ---------------------------------------------------------------------------
__global__ __launch_bounds__(512) void attn_chunk(
    const float* __restrict__ Q, const float* __restrict__ V,
    const float* __restrict__ Km, const float* __restrict__ Sx,
    const float* __restrict__ decay, float* __restrict__ Y) {
  const int bc = blockIdx.x;
  const int c = bc & 15;
  const size_t row0 = (size_t)((bc >> 4) * TT + c * CH);
  const float* Qc = Q + row0 * PP;
  const float* Vc = V + row0 * PP;
  const float* Kc = Km + row0 * PP;
  const float* S  = Sx + (size_t)bc * (PP * PP);
  const float* dc = decay + c * CH;

  __shared__ float Am[CH][PP + 1];   // masked+scaled scores, 66 KB
  __shared__ float Ls[16][PP + 1];
  __shared__ float Rs[16][PP + 1];

  const int tid = threadIdx.x;
  const int rx = tid & 31;   // cols rx*4 .. +3
  const int ry = tid >> 5;   // rows ry*8 .. +7

  // ---- phase 1: A[t][s] = dot_i(Q[t,i], V[s,i]) ----
  float acc[8][4] = {};
  for (int i0 = 0; i0 < PP; i0 += 16) {
#pragma unroll
    for (int i = 0; i < 4; ++i) {
      int idx = tid + i * 512;
      int t = idx >> 4, k = idx & 15;               // transposed stage
      Ls[k][t] = Qc[(size_t)t * PP + i0 + k];
      Rs[k][t] = Vc[(size_t)t * PP + i0 + k];
    }
    __syncthreads();
#pragma unroll
    for (int k = 0; k < 16; ++k) {
      float a[8], bv[4];
#pragma unroll
      for (int i = 0; i < 8; ++i) a[i] = Ls[k][ry * 8 + i];
#pragma unroll
      for (int j = 0; j < 4; ++j) bv[j] = Rs[k][rx * 4 + j];
#pragma unroll
      for (int i = 0; i < 8; ++i)
#pragma unroll
        for (int j = 0; j < 4; ++j) acc[i][j] += a[i] * bv[j];
    }
    __syncthreads();
  }
  // causal mask + per-source decay
#pragma unroll
  for (int i = 0; i < 8; ++i) {
    int t = ry * 8 + i;
#pragma unroll
    for (int j = 0; j < 4; ++j) {
      int s = rx * 4 + j;
      Am[t][s] = (s <= t) ? acc[i][j] * dc[s] : 0.f;
    }
  }

  // ---- phase 2: Y = Am @ K_c + Q_c @ S ----
  float y[8][4] = {};
  for (int s0 = 0; s0 < CH; s0 += 16) {
#pragma unroll
    for (int i = 0; i < 4; ++i) {
      int idx = tid + i * 512;
      int k = idx >> 7, n = idx & 127;
      Rs[k][n] = Kc[(size_t)(s0 + k) * PP + n];
    }
    __syncthreads();
#pragma unroll
    for (int k = 0; k < 16; ++k) {
      float a[8], bv[4];
#pragma unroll
      for (int i = 0; i < 8; ++i) a[i] = Am[ry * 8 + i][s0 + k];
#pragma unroll
      for (int j = 0; j < 4; ++j) bv[j] = Rs[k][rx * 4 + j];
#pragma unroll
      for (int i = 0; i < 8; ++i)
#pragma unroll
        for (int j = 0; j < 4; ++j) y[i][j] += a[i] * bv[j];
    }
    __syncthreads();
  }
  for (int i0 = 0; i0 < PP; i0 += 16) {
#pragma unroll
    for (int i = 0; i < 4; ++i) {
      int idx = tid + i * 512;
      {
        int t = idx >> 4, k = idx & 15;
        Ls[k][t] = Qc[(size_t)t * PP + i0 + k];
      }
      {
        int k = idx >> 7, n = idx & 127;
        Rs[k][n] = S[(size_t)(i0 + k) * PP + n];
      }
    }
    __syncthreads();
#pragma unroll
    for (int k = 0; k < 16; ++k) {
      float a[8], bv[4];
#pragma unroll
      for (int i = 0; i < 8; ++i) a[i] = Ls[k][ry * 8 + i];
#pragma unroll
      for (int j = 0; j < 4; ++j) bv[j] = Rs[k][rx * 4 + j];
#pragma unroll
      for (int i = 0; i < 8; ++i)
#pragma unroll
        for (int j = 0; j < 4; ++j) y[i][j] += a[i] * bv[j];
    }
    __syncthreads();
  }

#pragma unroll
  for (int i = 0; i < 8; ++i) {
    size_t t = row0 + ry * 8 + i;
#pragma unroll
    for (int j = 0; j < 4; ++j)
      Y[t * PP + rx * 4 + j] = y[i][j];
  }
}

// ---------------------------------------------------------------------------
extern "C" void kernel_launch(void* const* d_in, const int* in_sizes, int n_in,
                              void* d_out, int out_size, void* d_ws, size_t ws_size,
                              hipStream_t stream) {
  const float* x     = (const float*)d_in[0];
  const float* Qf    = (const float*)d_in[1];
  const float* Kf    = (const float*)d_in[2];
  const float* W_in  = (const float*)d_in[3];
  const float* b_in  = (const float*)d_in[4];
  const float* W_v   = (const float*)d_in[5];
  const float* b_v   = (const float*)d_in[6];
  const float* W_o   = (const float*)d_in[7];
  const float* b_o   = (const float*)d_in[8];
  const float* decay = (const float*)d_in[9];
  float* out = (float*)d_out;
  float* ws  = (float*)d_ws;

  const size_t NTP = (size_t)BB * TT * PP;  // 1M elements per (B,T,P) buffer
  float* xp = ws;             // x @ W_in + b_in        [freed after Q,K]
  float* V  = ws + 1 * NTP;
  float* Qm = ws + 2 * NTP;
  float* Km = ws + 3 * NTP;
  float* Sc = ws + 4 * NTP;   // per-chunk states  (B*NC*128*128 = 1M)
  float* Sxp= ws + 5 * NTP;   // exclusive prefix states
  float* Y  = ws;             // reuse xp slot for attention output

  const int M = BB * TT;  // 8192
  dim3 blk(256);

  // projections
  gemm_bias<<<dim3(PP / BN, M / BM), blk, 0, stream>>>(x, W_in, b_in, xp, M, PP, DD);
  gemm_bias<<<dim3(PP / BN, M / BM), blk, 0, stream>>>(x, W_v, b_v, V, M, PP, DD);
  gemm_bias<<<dim3(PP / BN, M / BM), blk, 0, stream>>>(xp, Qf, nullptr, Qm, M, PP, PP);
  gemm_bias<<<dim3(PP / BN, M / BM), blk, 0, stream>>>(xp, Kf, nullptr, Km, M, PP, PP);

  // chunked linear attention
  chunk_state<<<dim3(2, 2, BB * NC), blk, 0, stream>>>(V, Km, decay, Sc);
  chunk_scan<<<dim3((PP * PP) / 256, BB), blk, 0, stream>>>(Sc, Sxp);
  attn_chunk<<<dim3(BB * NC), dim3(512), 0, stream>>>(Qm, V, Km, Sxp, decay, Y);

  // output projection
  gemm_bias<<<dim3(DD / BN, M / BM), blk, 0, stream>>>(Y, W_o, b_o, out, M, DD, PP);
}

// Round 2
// 94.447 us; speedup vs baseline: 4.0275x; 4.0275x over previous
//
#include <hip/hip_runtime.h>

// B=4, T=2048, D=1024, P=128
#define BB 4
#define TT 2048
#define DD 1024
#define PP 128
#define NC 16
#define CH 128

typedef __attribute__((ext_vector_type(8))) short bf16x8;
typedef __attribute__((ext_vector_type(4))) float f32x4;

__device__ inline ushort f2bf(float f) {
  unsigned u = __builtin_bit_cast(unsigned, f);
  u = (u + 0x7FFF + ((u >> 16) & 1)) >> 16;   // RNE
  return (ushort)u;
}

__device__ inline void gll16(const void* g, void* l) {
  __builtin_amdgcn_global_load_lds(
      (const __attribute__((address_space(1))) void*)g,
      (__attribute__((address_space(3))) void*)l, 16, 0, 0);
}

// ---------------------------------------------------------------------------
// x fp32 -> bf16
// ---------------------------------------------------------------------------
__global__ __launch_bounds__(256) void conv_x(const float* __restrict__ x,
                                              ushort* __restrict__ xb, int n4) {
  int i = blockIdx.x * 256 + threadIdx.x;
  int stride = gridDim.x * 256;
  for (; i < n4; i += stride) {
    float4 v = ((const float4*)x)[i];
    ushort4 o;
    o.x = f2bf(v.x); o.y = f2bf(v.y); o.z = f2bf(v.z); o.w = f2bf(v.w);
    ((ushort4*)xb)[i] = o;
  }
}

// ---------------------------------------------------------------------------
// Weight prep: WcatT[256][1024] = [W_in|W_v]^T bf16; QKcatT[256][128] =
// [Qf|Kf]^T; WoT[1024][128] = W_o^T; bcat[256] = [b_in|b_v] fp32.
// ---------------------------------------------------------------------------
__global__ __launch_bounds__(256) void prep_w(
    const float* __restrict__ Qf, const float* __restrict__ Kf,
    const float* __restrict__ W_in, const float* __restrict__ b_in,
    const float* __restrict__ W_v, const float* __restrict__ b_v,
    const float* __restrict__ W_o,
    ushort* __restrict__ WcatT, ushort* __restrict__ QKcatT,
    ushort* __restrict__ WoT, float* __restrict__ bcat) {
  int i = blockIdx.x * 256 + threadIdx.x;
  if (i < 262144) {                       // WcatT
    int n = i & 255, k = i >> 8;          // k < 1024
    float v = (n < 128) ? W_in[k * 128 + n] : W_v[k * 128 + (n - 128)];
    WcatT[(size_t)n * 1024 + k] = f2bf(v);
  } else if (i < 262144 + 32768) {        // QKcatT
    int j = i - 262144;
    int n = j & 255, k = j >> 8;          // k < 128
    float v = (n < 128) ? Qf[k * 128 + n] : Kf[k * 128 + (n - 128)];
    QKcatT[n * 128 + k] = f2bf(v);
  } else if (i < 294912 + 131072) {       // WoT
    int j = i - 294912;
    int n = j & 1023, k = j >> 10;        // k < 128
    WoT[(size_t)n * 128 + k] = f2bf(W_o[(size_t)k * 1024 + n]);
  } else if (i < 425984 + 256) {          // bcat
    int j = i - 425984;
    bcat[j] = (j < 128) ? b_in[j] : b_v[j - 128];
  }
}

// ---------------------------------------------------------------------------
// MFMA GEMM: C[M,N] = A[M,K](bf16,lda) @ B (given as BT[N,K] bf16, ldb)
// 128x128 tile, BK=32, 256 threads (4 waves 2x2, each 64x64).
// MODE 0: +bcat bias; col<128 -> XP bf16[*,128]; col>=128 -> V bf16 + VT[c][row]
// MODE 1: no bias;    col<128 -> Qb bf16;        col>=128 -> KT[c][row], KdT (decay-scaled)
// MODE 2: fp32 out = acc + bias
// ---------------------------------------------------------------------------
template <int MODE>
__global__ __launch_bounds__(256) void mfma_gemm(
    const ushort* __restrict__ A, int lda,
    const ushort* __restrict__ BT, int ldb,
    const float* __restrict__ bias,
    void* __restrict__ o0, void* __restrict__ o1, void* __restrict__ o2,
    const float* __restrict__ decay, int M, int N, int K) {
  __shared__ ushort As[128 * 32];
  __shared__ ushort Bs[128 * 32];
  const int tid = threadIdx.x;
  const int w = tid >> 6, l = tid & 63;
  const int wr = w >> 1, wc = w & 1, lr = l & 15, lk = l >> 4;
  const int bm = blockIdx.y * 128, bn = blockIdx.x * 128;
  const int sr = tid >> 2, sc = (tid & 3) * 8;
  const ushort* Ag = A + (size_t)(bm + sr) * lda + sc;
  const ushort* Bg = BT + (size_t)(bn + sr) * ldb + sc;
  ushort* AsW = As + w * 512;  // bytes w*1024
  ushort* BsW = Bs + w * 512;

  f32x4 z = {0.f, 0.f, 0.f, 0.f};
  f32x4 acc[4][4];
#pragma unroll
  for (int m = 0; m < 4; ++m)
#pragma unroll
    for (int n = 0; n < 4; ++n) acc[m][n] = z;

  for (int k0 = 0; k0 < K; k0 += 32) {
    gll16(Ag, AsW);
    gll16(Ag + (size_t)64 * lda, AsW + 2048);
    gll16(Bg, BsW);
    gll16(Bg + (size_t)64 * ldb, BsW + 2048);
    Ag += 32; Bg += 32;
    __syncthreads();
    bf16x8 af[4], bf[4];
#pragma unroll
    for (int m = 0; m < 4; ++m)
      af[m] = *(const bf16x8*)&As[(wr * 64 + m * 16 + lr) * 32 + lk * 8];
#pragma unroll
    for (int n = 0; n < 4; ++n)
      bf[n] = *(const bf16x8*)&Bs[(wc * 64 + n * 16 + lr) * 32 + lk * 8];
#pragma unroll
    for (int m = 0; m < 4; ++m)
#pragma unroll
      for (int n = 0; n < 4; ++n)
        acc[m][n] = __builtin_amdgcn_mfma_f32_16x16x32_bf16(af[m], bf[n], acc[m][n], 0, 0, 0);
    __syncthreads();
  }

#pragma unroll
  for (int m = 0; m < 4; ++m)
#pragma unroll
    for (int n = 0; n < 4; ++n) {
      const int col = bn + wc * 64 + n * 16 + lr;
      const int rowb = bm + wr * 64 + m * 16 + lk * 4;
      if (MODE == 2) {
        float* C = (float*)o0;
        float bv = bias[col];
#pragma unroll
        for (int j = 0; j < 4; ++j)
          C[(size_t)(rowb + j) * N + col] = acc[m][n][j] + bv;
      } else if (MODE == 0) {
        ushort* XP = (ushort*)o0;
        ushort* Vv = (ushort*)o1;
        ushort* VT = (ushort*)o2;
        float bv = bias[col];
        if (col < 128) {
#pragma unroll
          for (int j = 0; j < 4; ++j)
            XP[(size_t)(rowb + j) * 128 + col] = f2bf(acc[m][n][j] + bv);
        } else {
          int cc = col - 128;
          ushort4 pk;
#pragma unroll
          for (int j = 0; j < 4; ++j) {
            ushort u = f2bf(acc[m][n][j] + bv);
            Vv[(size_t)(rowb + j) * 128 + cc] = u;
            ((ushort*)&pk)[j] = u;
          }
          *(ushort4*)&VT[(size_t)cc * 8192 + rowb] = pk;
        }
      } else {  // MODE 1
        ushort* Qb = (ushort*)o0;
        ushort* KT = (ushort*)o1;
        ushort* KdT = (ushort*)o2;
        if (col < 128) {
#pragma unroll
          for (int j = 0; j < 4; ++j)
            Qb[(size_t)(rowb + j) * 128 + col] = f2bf(acc[m][n][j]);
        } else {
          int cc = col - 128;
          ushort4 pk, pkd;
#pragma unroll
          for (int j = 0; j < 4; ++j) {
            float v = acc[m][n][j];
            ((ushort*)&pk)[j] = f2bf(v);
            ((ushort*)&pkd)[j] = f2bf(v * decay[(rowb + j) & (TT - 1)]);
          }
          *(ushort4*)&KT[(size_t)cc * 8192 + rowb] = pk;
          *(ushort4*)&KdT[(size_t)cc * 8192 + rowb] = pkd;
        }
      }
    }
}

// ---------------------------------------------------------------------------
// Per-chunk state S^T[j][i] = sum_s Kd[s][j] * V[s][i]  (MFMA, global-direct)
// ---------------------------------------------------------------------------
__global__ __launch_bounds__(256) void chunk_state_mfma(
    const ushort* __restrict__ KdT, const ushort* __restrict__ VT,
    float* __restrict__ Sc) {
  const int bc = blockIdx.x, b = bc >> 4, c = bc & 15;
  const size_t s0 = (size_t)b * TT + c * CH;
  const int tid = threadIdx.x, w = tid >> 6, l = tid & 63;
  const int wr = w >> 1, wc = w & 1, lr = l & 15, lk = l >> 4;
  f32x4 z = {0.f, 0.f, 0.f, 0.f};
  f32x4 acc[4][4];
#pragma unroll
  for (int m = 0; m < 4; ++m)
#pragma unroll
    for (int n = 0; n < 4; ++n) acc[m][n] = z;
#pragma unroll
  for (int ks = 0; ks < 4; ++ks) {
    const int kk = ks * 32 + lk * 8;
    bf16x8 af[4], bf[4];
#pragma unroll
    for (int m = 0; m < 4; ++m)
      af[m] = *(const bf16x8*)&KdT[(size_t)(wr * 64 + m * 16 + lr) * 8192 + s0 + kk];
#pragma unroll
    for (int n = 0; n < 4; ++n)
      bf[n] = *(const bf16x8*)&VT[(size_t)(wc * 64 + n * 16 + lr) * 8192 + s0 + kk];
#pragma unroll
    for (int m = 0; m < 4; ++m)
#pragma unroll
      for (int n = 0; n < 4; ++n)
        acc[m][n] = __builtin_amdgcn_mfma_f32_16x16x32_bf16(af[m], bf[n], acc[m][n], 0, 0, 0);
  }
#pragma unroll
  for (int m = 0; m < 4; ++m)
#pragma unroll
    for (int n = 0; n < 4; ++n)
#pragma unroll
      for (int j = 0; j < 4; ++j)
        Sc[(size_t)bc * 16384 + (size_t)(wr * 64 + m * 16 + lk * 4 + j) * 128 +
           (wc * 64 + n * 16 + lr)] = acc[m][n][j];
}

// ---------------------------------------------------------------------------
// Exclusive prefix over chunks -> SxT bf16 (layout [bc][j][i] = S^T)
// ---------------------------------------------------------------------------
__global__ __launch_bounds__(256) void chunk_scan(const float* __restrict__ Sc,
                                                  ushort* __restrict__ SxT) {
  int b = blockIdx.y;
  int e = blockIdx.x * 256 + threadIdx.x;
  float run = 0.f;
#pragma unroll
  for (int c = 0; c < NC; ++c) {
    size_t idx = ((size_t)(b * NC + c)) * 16384 + e;
    SxT[idx] = f2bf(run);
    run += Sc[idx];
  }
}

// ---------------------------------------------------------------------------
// Attention core per (b,c): Y = tril(Q V^T ⊙ d_s) K + Q Sx     (all MFMA)
// ---------------------------------------------------------------------------
__global__ __launch_bounds__(256) void attn_mfma(
    const ushort* __restrict__ Qb, const ushort* __restrict__ V,
    const ushort* __restrict__ KT, const ushort* __restrict__ SxT,
    const float* __restrict__ decay, ushort* __restrict__ Y) {
  __shared__ ushort Am[128 * 128];  // swizzled scores, 32 KB
  const int bc = blockIdx.x, b = bc >> 4, c = bc & 15;
  const size_t r0 = (size_t)b * TT + c * CH;
  const int tid = threadIdx.x, w = tid >> 6, l = tid & 63;
  const int wr = w >> 1, wc = w & 1, lr = l & 15, lk = l >> 4;
  const float* dc = decay + c * CH;

  f32x4 z = {0.f, 0.f, 0.f, 0.f};
  f32x4 a1[4][4];
#pragma unroll
  for (int m = 0; m < 4; ++m)
#pragma unroll
    for (int n = 0; n < 4; ++n) a1[m][n] = z;

  // phase 1: scores = Q V^T
#pragma unroll
  for (int ks = 0; ks < 4; ++ks) {
    const int kk = ks * 32 + lk * 8;
    bf16x8 af[4], bf[4];
#pragma unroll
    for (int m = 0; m < 4; ++m)
      af[m] = *(const bf16x8*)&Qb[(r0 + wr * 64 + m * 16 + lr) * 128 + kk];
#pragma unroll
    for (int n = 0; n < 4; ++n)
      bf[n] = *(const bf16x8*)&V[(r0 + wc * 64 + n * 16 + lr) * 128 + kk];
#pragma unroll
    for (int m = 0; m < 4; ++m)
#pragma unroll
      for (int n = 0; n < 4; ++n)
        a1[m][n] = __builtin_amdgcn_mfma_f32_16x16x32_bf16(af[m], bf[n], a1[m][n], 0, 0, 0);
  }
  // mask + decay -> LDS (XOR-swizzled rows)
#pragma unroll
  for (int m = 0; m < 4; ++m)
#pragma unroll
    for (int n = 0; n < 4; ++n)
#pragma unroll
      for (int j = 0; j < 4; ++j) {
        int t = wr * 64 + m * 16 + lk * 4 + j;
        int s = wc * 64 + n * 16 + lr;
        float v = (s <= t) ? a1[m][n][j] * dc[s] : 0.f;
        int byte = t * 256 + ((s * 2) ^ ((t & 7) << 4));
        *(ushort*)((char*)Am + byte) = f2bf(v);
      }
  __syncthreads();

  // phase 2: Y = Am @ K + Q @ Sx
  f32x4 a2[4][4];
#pragma unroll
  for (int m = 0; m < 4; ++m)
#pragma unroll
    for (int n = 0; n < 4; ++n) a2[m][n] = z;
#pragma unroll
  for (int ks = 0; ks < 4; ++ks) {
    const int kk = ks * 32 + lk * 8;
    bf16x8 af[4], bf[4];
#pragma unroll
    for (int m = 0; m < 4; ++m) {
      int t = wr * 64 + m * 16 + lr;
      af[m] = *(const bf16x8*)((char*)Am + t * 256 + ((kk * 2) ^ ((t & 7) << 4)));
    }
#pragma unroll
    for (int n = 0; n < 4; ++n)
      bf[n] = *(const bf16x8*)&KT[(size_t)(wc * 64 + n * 16 + lr) * 8192 + r0 + kk];
#pragma unroll
    for (int m = 0; m < 4; ++m)
#pragma unroll
      for (int n = 0; n < 4; ++n)
        a2[m][n] = __builtin_amdgcn_mfma_f32_16x16x32_bf16(af[m], bf[n], a2[m][n], 0, 0, 0);
  }
#pragma unroll
  for (int ks = 0; ks < 4; ++ks) {
    const int kk = ks * 32 + lk * 8;
    bf16x8 af[4], bf[4];
#pragma unroll
    for (int m = 0; m < 4; ++m)
      af[m] = *(const bf16x8*)&Qb[(r0 + wr * 64 + m * 16 + lr) * 128 + kk];
#pragma unroll
    for (int n = 0; n < 4; ++n)
      bf[n] = *(const bf16x8*)&SxT[(size_t)bc * 16384 + (size_t)(wc * 64 + n * 16 + lr) * 128 + kk];
#pragma unroll
    for (int m = 0; m < 4; ++m)
#pragma unroll
      for (int n = 0; n < 4; ++n)
        a2[m][n] = __builtin_amdgcn_mfma_f32_16x16x32_bf16(af[m], bf[n], a2[m][n], 0, 0, 0);
  }
#pragma unroll
  for (int m = 0; m < 4; ++m)
#pragma unroll
    for (int n = 0; n < 4; ++n)
#pragma unroll
      for (int j = 0; j < 4; ++j) {
        int t = wr * 64 + m * 16 + lk * 4 + j;
        int col = wc * 64 + n * 16 + lr;
        Y[(r0 + t) * 128 + col] = f2bf(a2[m][n][j]);
      }
}

// ---------------------------------------------------------------------------
extern "C" void kernel_launch(void* const* d_in, const int* in_sizes, int n_in,
                              void* d_out, int out_size, void* d_ws, size_t ws_size,
                              hipStream_t stream) {
  const float* x = (const float*)d_in[0];
  const float* Qf = (const float*)d_in[1];
  const float* Kf = (const float*)d_in[2];
  const float* W_in = (const float*)d_in[3];
  const float* b_in = (const float*)d_in[4];
  const float* W_v = (const float*)d_in[5];
  const float* b_v = (const float*)d_in[6];
  const float* W_o = (const float*)d_in[7];
  const float* b_o = (const float*)d_in[8];
  const float* decay = (const float*)d_in[9];
  float* out = (float*)d_out;
  char* W = (char*)d_ws;

  ushort* xb    = (ushort*)(W);                    // 16,777,216 B
  ushort* XP    = (ushort*)(W + 16777216);         // 2,097,152 each
  ushort* V     = (ushort*)(W + 18874368);
  ushort* VT    = (ushort*)(W + 20971520);
  ushort* Qb    = (ushort*)(W + 23068672);
  ushort* KT    = (ushort*)(W + 25165824);
  ushort* KdT   = (ushort*)(W + 27262976);
  ushort* WcatT = (ushort*)(W + 29360128);         // 524,288
  ushort* QKcT  = (ushort*)(W + 29884416);         // 65,536
  ushort* WoT   = (ushort*)(W + 29949952);         // 262,144
  float*  bcat  = (float*)(W + 30212096);          // 1,024
  // overlays in xb region (xb dead after GEMM1):
  float*  Sc    = (float*)(W);                     // 4,194,304
  ushort* SxT   = (ushort*)(W + 4194304);          // 2,097,152
  ushort* Y     = (ushort*)(W + 6291456);          // 2,097,152

  conv_x<<<2048, 256, 0, stream>>>(x, xb, (BB * TT * DD) / 4);
  prep_w<<<1665, 256, 0, stream>>>(Qf, Kf, W_in, b_in, W_v, b_v, W_o,
                                   WcatT, QKcT, WoT, bcat);
  // x @ [W_in|W_v] + [b_in|b_v]  -> XP(bf16), V(bf16), VT(bf16 transposed)
  mfma_gemm<0><<<dim3(2, 64), 256, 0, stream>>>(xb, DD, WcatT, DD, bcat,
                                                XP, V, VT, nullptr, BB * TT, 256, DD);
  // XP @ [Qf|Kf] -> Qb, KT, KdT(decay-folded)
  mfma_gemm<1><<<dim3(2, 64), 256, 0, stream>>>(XP, PP, QKcT, PP, nullptr,
                                                Qb, KT, KdT, decay, BB * TT, 256, PP);
  chunk_state_mfma<<<BB * NC, 256, 0, stream>>>(KdT, VT, Sc);
  chunk_scan<<<dim3(64, BB), 256, 0, stream>>>(Sc, SxT);
  attn_mfma<<<BB * NC, 256, 0, stream>>>(Qb, V, KT, SxT, decay, Y);
  // out = Y @ W_o + b_o (fp32)
  mfma_gemm<2><<<dim3(8, 64), 256, 0, stream>>>(Y, PP, WoT, PP, b_o,
                                                out, nullptr, nullptr, nullptr,
                                                BB * TT, DD, PP);
}

// Round 3
// 76.402 us; speedup vs baseline: 4.9787x; 1.2362x over previous
//
#include <hip/hip_runtime.h>

// B=4, T=2048, D=1024, P=128
#define BB 4
#define TT 2048
#define DD 1024
#define PP 128
#define NC 16
#define CH 128

typedef __attribute__((ext_vector_type(8))) short bf16x8;
typedef __attribute__((ext_vector_type(4))) float f32x4;

__device__ inline ushort f2bf(float f) {
  unsigned u = __builtin_bit_cast(unsigned, f);
  u = (u + 0x7FFF + ((u >> 16) & 1)) >> 16;  // RNE
  return (ushort)u;
}

__device__ inline void gll16(const void* g, void* l) {
  __builtin_amdgcn_global_load_lds(
      (const __attribute__((address_space(1))) void*)g,
      (__attribute__((address_space(3))) void*)l, 16, 0, 0);
}

// T2 swizzle: LDS tiles are [rows][128] bf16 (256B rows); byte-bit 4..6 of the
// k-offset is XORed with (row&7) so 16-lane column reads spread over 8 bank
// slots (2-way = free). gll16 writes stay linear; the SOURCE address carries
// the inverse permutation (involution), per rule #21.
__device__ inline int swzoff(int row, int kbyte) {
  return row * 256 + (kbyte ^ ((row & 7) << 4));
}

template <int NI>
__device__ inline void stage_swz(const ushort* __restrict__ g, int ld, int koff,
                                 char* lds, int tid) {
#pragma unroll
  for (int j = 0; j < NI; ++j) {
    int L = j * 4096 + tid * 16;
    int row = L >> 8;
    int off = (L & 255) ^ ((row & 7) << 4);
    gll16(g + (size_t)row * ld + koff + (off >> 1),
          lds + j * 4096 + ((tid & 192) << 4));
  }
}

__device__ inline bf16x8 ld_swz(const char* lds, int row, int kbyte) {
  return *(const bf16x8*)(lds + swzoff(row, kbyte));
}

// ---------------------------------------------------------------------------
// Fused prep: x fp32->bf16, plus transposed bf16 weights and bias concat.
// ---------------------------------------------------------------------------
__global__ __launch_bounds__(256) void prep(
    const float* __restrict__ x, const float* __restrict__ Qf,
    const float* __restrict__ Kf, const float* __restrict__ W_in,
    const float* __restrict__ b_in, const float* __restrict__ W_v,
    const float* __restrict__ b_v, const float* __restrict__ W_o,
    ushort* __restrict__ xb, ushort* __restrict__ WcatT,
    ushort* __restrict__ QKcT, ushort* __restrict__ WoT,
    float* __restrict__ bcat) {
  const int NCONV = (BB * TT * DD) / 4;  // 2,097,152 float4 groups
  int i = blockIdx.x * 256 + threadIdx.x;
  const int stride = gridDim.x * 256;
  for (; i < NCONV + 426240; i += stride) {
    if (i < NCONV) {
      float4 v = ((const float4*)x)[i];
      ushort4 o;
      o.x = f2bf(v.x); o.y = f2bf(v.y); o.z = f2bf(v.z); o.w = f2bf(v.w);
      ((ushort4*)xb)[i] = o;
    } else {
      int j = i - NCONV;
      if (j < 262144) {                    // WcatT[256][1024]
        int n = j & 255, k = j >> 8;
        float v = (n < 128) ? W_in[k * 128 + n] : W_v[k * 128 + (n - 128)];
        WcatT[(size_t)n * 1024 + k] = f2bf(v);
      } else if (j < 294912) {             // QKcT[256][128]
        int jj = j - 262144;
        int n = jj & 255, k = jj >> 8;
        float v = (n < 128) ? Qf[k * 128 + n] : Kf[k * 128 + (n - 128)];
        QKcT[n * 128 + k] = f2bf(v);
      } else if (j < 425984) {             // WoT[1024][128]
        int jj = j - 294912;
        int n = jj & 1023, k = jj >> 10;
        WoT[(size_t)n * 128 + k] = f2bf(W_o[(size_t)k * 1024 + n]);
      } else {                             // bcat[256]
        int jj = j - 425984;
        bcat[jj] = (jj < 128) ? b_in[jj] : b_v[jj - 128];
      }
    }
  }
}

// ---------------------------------------------------------------------------
// GEMM1: [8192x1024] @ [1024x256] (BT layout) -> XP | V,VT.
// BM=64 BN=128 BK=128, double-buffered, counted vmcnt(12), 2 barriers/iter.
// grid 256 (T1 XCD swizzle: row-pair blocks share A tile in one XCD L2).
// ---------------------------------------------------------------------------
__global__ __launch_bounds__(256) void gemm_xw(
    const ushort* __restrict__ xb, const ushort* __restrict__ WcatT,
    const float* __restrict__ bcat, ushort* __restrict__ XP,
    ushort* __restrict__ V, ushort* __restrict__ VT) {
  __shared__ char sm[2][49152];  // [A 16K | B 32K] x2
  const int bid = blockIdx.x;
  const int swz = (bid & 7) * 32 + (bid >> 3);
  const int bm = (swz >> 1) * 64;
  const int bn = (swz & 1) * 128;
  const int tid = threadIdx.x, w = tid >> 6, l = tid & 63;
  const int wr = w >> 1, wc = w & 1, lr = l & 15, lk = l >> 4;
  const ushort* Ag = xb + (size_t)bm * DD;
  const ushort* Bg = WcatT + (size_t)bn * DD;

  f32x4 z = {0.f, 0.f, 0.f, 0.f};
  f32x4 acc[2][4];
#pragma unroll
  for (int m = 0; m < 2; ++m)
#pragma unroll
    for (int n = 0; n < 4; ++n) acc[m][n] = z;

  stage_swz<4>(Ag, DD, 0, sm[0], tid);
  stage_swz<8>(Bg, DD, 0, sm[0] + 16384, tid);
  int cur = 0;
  for (int t = 0; t < 8; ++t) {
    const int kn = ((t + 1) & 7) << 7;   // wrapped prefetch (last one harmless)
    char* nxt = sm[cur ^ 1];
    stage_swz<4>(Ag, DD, kn, nxt, tid);
    stage_swz<8>(Bg, DD, kn, nxt + 16384, tid);
    asm volatile("s_waitcnt vmcnt(12)" ::: "memory");  // current tile landed
    __builtin_amdgcn_s_barrier();
    const char* cp = sm[cur];
#pragma unroll
    for (int ks = 0; ks < 4; ++ks) {
      const int kb = ks * 64 + lk * 16;
      bf16x8 af[2], bfp[4];
#pragma unroll
      for (int m = 0; m < 2; ++m) af[m] = ld_swz(cp, wr * 32 + m * 16 + lr, kb);
#pragma unroll
      for (int n = 0; n < 4; ++n)
        bfp[n] = ld_swz(cp + 16384, wc * 64 + n * 16 + lr, kb);
#pragma unroll
      for (int m = 0; m < 2; ++m)
#pragma unroll
        for (int n = 0; n < 4; ++n)
          acc[m][n] = __builtin_amdgcn_mfma_f32_16x16x32_bf16(af[m], bfp[n], acc[m][n], 0, 0, 0);
    }
    __builtin_amdgcn_s_barrier();        // reads done before next overwrite
    cur ^= 1;
  }
  asm volatile("s_waitcnt vmcnt(0)" ::: "memory");  // drain wasted prefetch

#pragma unroll
  for (int m = 0; m < 2; ++m)
#pragma unroll
    for (int n = 0; n < 4; ++n) {
      const int rowb = bm + wr * 32 + m * 16 + lk * 4;
      const int col = bn + wc * 64 + n * 16 + lr;
      const float bv = bcat[col];
      if (bn == 0) {
#pragma unroll
        for (int j = 0; j < 4; ++j)
          XP[(size_t)(rowb + j) * PP + col] = f2bf(acc[m][n][j] + bv);
      } else {
        const int cc = col - 128;
        ushort4 pk;
#pragma unroll
        for (int j = 0; j < 4; ++j) {
          ushort u = f2bf(acc[m][n][j] + bv);
          V[(size_t)(rowb + j) * PP + cc] = u;
          ((ushort*)&pk)[j] = u;
        }
        *(ushort4*)&VT[(size_t)cc * (BB * TT) + rowb] = pk;
      }
    }
}

// ---------------------------------------------------------------------------
// GEMM2: XP[8192x128] @ QKcat[128x256] -> Qb | KT,KdT. Single-shot K=128.
// BM=64, BN=256 (full). grid 128.
// ---------------------------------------------------------------------------
__global__ __launch_bounds__(256) void gemm_qk(
    const ushort* __restrict__ XP, const ushort* __restrict__ QKcT,
    const float* __restrict__ decay, ushort* __restrict__ Qb,
    ushort* __restrict__ KT, ushort* __restrict__ KdT) {
  __shared__ char sm[81920];  // A 16K | B 64K
  const int bm = blockIdx.x * 64;
  const int tid = threadIdx.x, w = tid >> 6, l = tid & 63;
  const int lr = l & 15, lk = l >> 4;
  stage_swz<4>(XP + (size_t)bm * PP, PP, 0, sm, tid);
  stage_swz<16>(QKcT, PP, 0, sm + 16384, tid);
  f32x4 z = {0.f, 0.f, 0.f, 0.f};
  f32x4 acc[4][4];
#pragma unroll
  for (int m = 0; m < 4; ++m)
#pragma unroll
    for (int n = 0; n < 4; ++n) acc[m][n] = z;
  __syncthreads();
#pragma unroll
  for (int ks = 0; ks < 4; ++ks) {
    const int kb = ks * 64 + lk * 16;
    bf16x8 af[4], bfp[4];
#pragma unroll
    for (int m = 0; m < 4; ++m) af[m] = ld_swz(sm, m * 16 + lr, kb);
#pragma unroll
    for (int n = 0; n < 4; ++n)
      bfp[n] = ld_swz(sm + 16384, w * 64 + n * 16 + lr, kb);
#pragma unroll
    for (int m = 0; m < 4; ++m)
#pragma unroll
      for (int n = 0; n < 4; ++n)
        acc[m][n] = __builtin_amdgcn_mfma_f32_16x16x32_bf16(af[m], bfp[n], acc[m][n], 0, 0, 0);
  }
#pragma unroll
  for (int m = 0; m < 4; ++m)
#pragma unroll
    for (int n = 0; n < 4; ++n) {
      const int rowb = bm + m * 16 + lk * 4;
      const int col = w * 64 + n * 16 + lr;
      if (col < 128) {
#pragma unroll
        for (int j = 0; j < 4; ++j)
          Qb[(size_t)(rowb + j) * PP + col] = f2bf(acc[m][n][j]);
      } else {
        const int cc = col - 128;
        ushort4 pk, pkd;
#pragma unroll
        for (int j = 0; j < 4; ++j) {
          float v = acc[m][n][j];
          ((ushort*)&pk)[j] = f2bf(v);
          ((ushort*)&pkd)[j] = f2bf(v * decay[(rowb + j) & (TT - 1)]);
        }
        *(ushort4*)&KT[(size_t)cc * (BB * TT) + rowb] = pk;
        *(ushort4*)&KdT[(size_t)cc * (BB * TT) + rowb] = pkd;
      }
    }
}

// ---------------------------------------------------------------------------
// Per-chunk state S^T[j][i] = sum_s Kd[s][j]*V[s][i]  (global-direct MFMA)
// ---------------------------------------------------------------------------
__global__ __launch_bounds__(256) void chunk_state_mfma(
    const ushort* __restrict__ KdT, const ushort* __restrict__ VT,
    float* __restrict__ Sc) {
  const int bc = blockIdx.x, b = bc >> 4, c = bc & 15;
  const size_t s0 = (size_t)b * TT + c * CH;
  const int tid = threadIdx.x, w = tid >> 6, l = tid & 63;
  const int wr = w >> 1, wc = w & 1, lr = l & 15, lk = l >> 4;
  f32x4 z = {0.f, 0.f, 0.f, 0.f};
  f32x4 acc[4][4];
#pragma unroll
  for (int m = 0; m < 4; ++m)
#pragma unroll
    for (int n = 0; n < 4; ++n) acc[m][n] = z;
#pragma unroll
  for (int ks = 0; ks < 4; ++ks) {
    const int kk = ks * 32 + lk * 8;
    bf16x8 af[4], bf[4];
#pragma unroll
    for (int m = 0; m < 4; ++m)
      af[m] = *(const bf16x8*)&KdT[(size_t)(wr * 64 + m * 16 + lr) * 8192 + s0 + kk];
#pragma unroll
    for (int n = 0; n < 4; ++n)
      bf[n] = *(const bf16x8*)&VT[(size_t)(wc * 64 + n * 16 + lr) * 8192 + s0 + kk];
#pragma unroll
    for (int m = 0; m < 4; ++m)
#pragma unroll
      for (int n = 0; n < 4; ++n)
        acc[m][n] = __builtin_amdgcn_mfma_f32_16x16x32_bf16(af[m], bf[n], acc[m][n], 0, 0, 0);
  }
#pragma unroll
  for (int m = 0; m < 4; ++m)
#pragma unroll
    for (int n = 0; n < 4; ++n)
#pragma unroll
      for (int j = 0; j < 4; ++j)
        Sc[(size_t)bc * 16384 + (size_t)(wr * 64 + m * 16 + lk * 4 + j) * 128 +
           (wc * 64 + n * 16 + lr)] = acc[m][n][j];
}

// ---------------------------------------------------------------------------
// Exclusive prefix over chunks -> SxT bf16
// ---------------------------------------------------------------------------
__global__ __launch_bounds__(256) void chunk_scan(const float* __restrict__ Sc,
                                                  ushort* __restrict__ SxT) {
  int b = blockIdx.y;
  int e = blockIdx.x * 256 + threadIdx.x;
  float run = 0.f;
#pragma unroll
  for (int c = 0; c < NC; ++c) {
    size_t idx = ((size_t)(b * NC + c)) * 16384 + e;
    SxT[idx] = f2bf(run);
    run += Sc[idx];
  }
}

// ---------------------------------------------------------------------------
// Attention core per (b,c): Y = tril(Q V^T ⊙ d_s) K + Q Sx
// ---------------------------------------------------------------------------
__global__ __launch_bounds__(256) void attn_mfma(
    const ushort* __restrict__ Qb, const ushort* __restrict__ V,
    const ushort* __restrict__ KT, const ushort* __restrict__ SxT,
    const float* __restrict__ decay, ushort* __restrict__ Y) {
  __shared__ ushort Am[128 * 128];
  const int bc = blockIdx.x, b = bc >> 4, c = bc & 15;
  const size_t r0 = (size_t)b * TT + c * CH;
  const int tid = threadIdx.x, w = tid >> 6, l = tid & 63;
  const int wr = w >> 1, wc = w & 1, lr = l & 15, lk = l >> 4;
  const float* dc = decay + c * CH;

  f32x4 z = {0.f, 0.f, 0.f, 0.f};
  f32x4 a1[4][4];
#pragma unroll
  for (int m = 0; m < 4; ++m)
#pragma unroll
    for (int n = 0; n < 4; ++n) a1[m][n] = z;

#pragma unroll
  for (int ks = 0; ks < 4; ++ks) {
    const int kk = ks * 32 + lk * 8;
    bf16x8 af[4], bf[4];
#pragma unroll
    for (int m = 0; m < 4; ++m)
      af[m] = *(const bf16x8*)&Qb[(r0 + wr * 64 + m * 16 + lr) * 128 + kk];
#pragma unroll
    for (int n = 0; n < 4; ++n)
      bf[n] = *(const bf16x8*)&V[(r0 + wc * 64 + n * 16 + lr) * 128 + kk];
#pragma unroll
    for (int m = 0; m < 4; ++m)
#pragma unroll
      for (int n = 0; n < 4; ++n)
        a1[m][n] = __builtin_amdgcn_mfma_f32_16x16x32_bf16(af[m], bf[n], a1[m][n], 0, 0, 0);
  }
#pragma unroll
  for (int m = 0; m < 4; ++m)
#pragma unroll
    for (int n = 0; n < 4; ++n)
#pragma unroll
      for (int j = 0; j < 4; ++j) {
        int t = wr * 64 + m * 16 + lk * 4 + j;
        int s = wc * 64 + n * 16 + lr;
        float v = (s <= t) ? a1[m][n][j] * dc[s] : 0.f;
        int byte = t * 256 + ((s * 2) ^ ((t & 7) << 4));
        *(ushort*)((char*)Am + byte) = f2bf(v);
      }
  __syncthreads();

  f32x4 a2[4][4];
#pragma unroll
  for (int m = 0; m < 4; ++m)
#pragma unroll
    for (int n = 0; n < 4; ++n) a2[m][n] = z;
#pragma unroll
  for (int ks = 0; ks < 4; ++ks) {
    const int kk = ks * 32 + lk * 8;
    bf16x8 af[4], bf[4];
#pragma unroll
    for (int m = 0; m < 4; ++m) {
      int t = wr * 64 + m * 16 + lr;
      af[m] = *(const bf16x8*)((char*)Am + t * 256 + ((kk * 2) ^ ((t & 7) << 4)));
    }
#pragma unroll
    for (int n = 0; n < 4; ++n)
      bf[n] = *(const bf16x8*)&KT[(size_t)(wc * 64 + n * 16 + lr) * 8192 + r0 + kk];
#pragma unroll
    for (int m = 0; m < 4; ++m)
#pragma unroll
      for (int n = 0; n < 4; ++n)
        a2[m][n] = __builtin_amdgcn_mfma_f32_16x16x32_bf16(af[m], bf[n], a2[m][n], 0, 0, 0);
  }
#pragma unroll
  for (int ks = 0; ks < 4; ++ks) {
    const int kk = ks * 32 + lk * 8;
    bf16x8 af[4], bf[4];
#pragma unroll
    for (int m = 0; m < 4; ++m)
      af[m] = *(const bf16x8*)&Qb[(r0 + wr * 64 + m * 16 + lr) * 128 + kk];
#pragma unroll
    for (int n = 0; n < 4; ++n)
      bf[n] = *(const bf16x8*)&SxT[(size_t)bc * 16384 + (size_t)(wc * 64 + n * 16 + lr) * 128 + kk];
#pragma unroll
    for (int m = 0; m < 4; ++m)
#pragma unroll
      for (int n = 0; n < 4; ++n)
        a2[m][n] = __builtin_amdgcn_mfma_f32_16x16x32_bf16(af[m], bf[n], a2[m][n], 0, 0, 0);
  }
#pragma unroll
  for (int m = 0; m < 4; ++m)
#pragma unroll
    for (int n = 0; n < 4; ++n)
#pragma unroll
      for (int j = 0; j < 4; ++j) {
        int t = wr * 64 + m * 16 + lk * 4 + j;
        int col = wc * 64 + n * 16 + lr;
        Y[(r0 + t) * 128 + col] = f2bf(a2[m][n][j]);
      }
}

// ---------------------------------------------------------------------------
// GEMM3: Y[8192x128] @ W_o[128x1024] + b_o -> out fp32. Single-shot K=128.
// BM=64 BN=128, grid 1024 (T1 swizzle).
// ---------------------------------------------------------------------------
__global__ __launch_bounds__(256) void gemm_out(
    const ushort* __restrict__ Y, const ushort* __restrict__ WoT,
    const float* __restrict__ b_o, float* __restrict__ out) {
  __shared__ char sm[49152];  // A 16K | B 32K
  const int bid = blockIdx.x;
  const int swz = (bid & 7) * 128 + (bid >> 3);
  const int bm = (swz >> 3) * 64, bn = (swz & 7) * 128;
  const int tid = threadIdx.x, w = tid >> 6, l = tid & 63;
  const int wr = w >> 1, wc = w & 1, lr = l & 15, lk = l >> 4;
  stage_swz<4>(Y + (size_t)bm * PP, PP, 0, sm, tid);
  stage_swz<8>(WoT + (size_t)bn * PP, PP, 0, sm + 16384, tid);
  f32x4 z = {0.f, 0.f, 0.f, 0.f};
  f32x4 acc[2][4];
#pragma unroll
  for (int m = 0; m < 2; ++m)
#pragma unroll
    for (int n = 0; n < 4; ++n) acc[m][n] = z;
  __syncthreads();
#pragma unroll
  for (int ks = 0; ks < 4; ++ks) {
    const int kb = ks * 64 + lk * 16;
    bf16x8 af[2], bfp[4];
#pragma unroll
    for (int m = 0; m < 2; ++m) af[m] = ld_swz(sm, wr * 32 + m * 16 + lr, kb);
#pragma unroll
    for (int n = 0; n < 4; ++n)
      bfp[n] = ld_swz(sm + 16384, wc * 64 + n * 16 + lr, kb);
#pragma unroll
    for (int m = 0; m < 2; ++m)
#pragma unroll
      for (int n = 0; n < 4; ++n)
        acc[m][n] = __builtin_amdgcn_mfma_f32_16x16x32_bf16(af[m], bfp[n], acc[m][n], 0, 0, 0);
  }
#pragma unroll
  for (int m = 0; m < 2; ++m)
#pragma unroll
    for (int n = 0; n < 4; ++n) {
      const int rowb = bm + wr * 32 + m * 16 + lk * 4;
      const int col = bn + wc * 64 + n * 16 + lr;
      const float bv = b_o[col];
#pragma unroll
      for (int j = 0; j < 4; ++j)
        out[(size_t)(rowb + j) * DD + col] = acc[m][n][j] + bv;
    }
}

// ---------------------------------------------------------------------------
extern "C" void kernel_launch(void* const* d_in, const int* in_sizes, int n_in,
                              void* d_out, int out_size, void* d_ws, size_t ws_size,
                              hipStream_t stream) {
  const float* x = (const float*)d_in[0];
  const float* Qf = (const float*)d_in[1];
  const float* Kf = (const float*)d_in[2];
  const float* W_in = (const float*)d_in[3];
  const float* b_in = (const float*)d_in[4];
  const float* W_v = (const float*)d_in[5];
  const float* b_v = (const float*)d_in[6];
  const float* W_o = (const float*)d_in[7];
  const float* b_o = (const float*)d_in[8];
  const float* decay = (const float*)d_in[9];
  float* out = (float*)d_out;
  char* W = (char*)d_ws;

  ushort* xb    = (ushort*)(W);
  ushort* XP    = (ushort*)(W + 16777216);
  ushort* V     = (ushort*)(W + 18874368);
  ushort* VT    = (ushort*)(W + 20971520);
  ushort* Qb    = (ushort*)(W + 23068672);
  ushort* KT    = (ushort*)(W + 25165824);
  ushort* KdT   = (ushort*)(W + 27262976);
  ushort* WcatT = (ushort*)(W + 29360128);
  ushort* QKcT  = (ushort*)(W + 29884416);
  ushort* WoT   = (ushort*)(W + 29949952);
  float*  bcat  = (float*)(W + 30212096);
  // overlays in xb region (xb dead after gemm_xw):
  float*  Sc    = (float*)(W);
  ushort* SxT   = (ushort*)(W + 4194304);
  ushort* Yb    = (ushort*)(W + 6291456);

  prep<<<4096, 256, 0, stream>>>(x, Qf, Kf, W_in, b_in, W_v, b_v, W_o,
                                 xb, WcatT, QKcT, WoT, bcat);
  gemm_xw<<<256, 256, 0, stream>>>(xb, WcatT, bcat, XP, V, VT);
  gemm_qk<<<128, 256, 0, stream>>>(XP, QKcT, decay, Qb, KT, KdT);
  chunk_state_mfma<<<BB * NC, 256, 0, stream>>>(KdT, VT, Sc);
  chunk_scan<<<dim3(64, BB), 256, 0, stream>>>(Sc, SxT);
  attn_mfma<<<BB * NC, 256, 0, stream>>>(Qb, V, KT, SxT, decay, Yb);
  gemm_out<<<1024, 256, 0, stream>>>(Yb, WoT, b_o, out);
}

// Round 4
// 68.873 us; speedup vs baseline: 5.5230x; 1.1093x over previous
//
#include <hip/hip_runtime.h>

// B=4, T=2048, D=1024, P=128
#define BB 4
#define TT 2048
#define DD 1024
#define PP 128
#define NC 16
#define CH 128

typedef __attribute__((ext_vector_type(8))) short bf16x8;
typedef __attribute__((ext_vector_type(4))) float f32x4;

__device__ inline ushort f2bf(float f) {
  unsigned u = __builtin_bit_cast(unsigned, f);
  u = (u + 0x7FFF + ((u >> 16) & 1)) >> 16;  // RNE
  return (ushort)u;
}

__device__ inline void gll16(const void* g, void* l) {
  __builtin_amdgcn_global_load_lds(
      (const __attribute__((address_space(1))) void*)g,
      (__attribute__((address_space(3))) void*)l, 16, 0, 0);
}

// T2 swizzle on [rows][128]bf16 tiles (256B rows): kbyte bits 4..6 ^= row&7.
// gll16 dests stay linear; SOURCE carries the inverse permutation (rule #21).
__device__ inline int swzoff(int row, int kbyte) {
  return row * 256 + (kbyte ^ ((row & 7) << 4));
}

template <int NI>
__device__ inline void stage_swz(const ushort* __restrict__ g, int ld, int koff,
                                 char* lds, int tid) {
#pragma unroll
  for (int j = 0; j < NI; ++j) {
    int L = j * 4096 + tid * 16;
    int row = L >> 8;
    int off = (L & 255) ^ ((row & 7) << 4);
    gll16(g + (size_t)row * ld + koff + (off >> 1),
          lds + j * 4096 + ((tid & 192) << 4));
  }
}

__device__ inline bf16x8 ld_swz(const char* lds, int row, int kbyte) {
  return *(const bf16x8*)(lds + swzoff(row, kbyte));
}

__device__ inline bf16x8 pack8(const float4& a, const float4& b) {
  bf16x8 v;
  v[0] = (short)f2bf(a.x); v[1] = (short)f2bf(a.y);
  v[2] = (short)f2bf(a.z); v[3] = (short)f2bf(a.w);
  v[4] = (short)f2bf(b.x); v[5] = (short)f2bf(b.y);
  v[6] = (short)f2bf(b.z); v[7] = (short)f2bf(b.w);
  return v;
}

// ---------------------------------------------------------------------------
// Weights-only prep: transposed bf16 weights + bias concat (~6.5 MB traffic).
// ---------------------------------------------------------------------------
__global__ __launch_bounds__(256) void prep_w(
    const float* __restrict__ Qf, const float* __restrict__ Kf,
    const float* __restrict__ W_in, const float* __restrict__ b_in,
    const float* __restrict__ W_v, const float* __restrict__ b_v,
    const float* __restrict__ W_o, ushort* __restrict__ WcatT,
    ushort* __restrict__ QKcT, ushort* __restrict__ WoT,
    float* __restrict__ bcat) {
  int i = blockIdx.x * 256 + threadIdx.x;
  if (i < 262144) {                    // WcatT[256][1024]
    int n = i & 255, k = i >> 8;
    float v = (n < 128) ? W_in[k * 128 + n] : W_v[k * 128 + (n - 128)];
    WcatT[(size_t)n * 1024 + k] = f2bf(v);
  } else if (i < 294912) {             // QKcT[256][128]
    int j = i - 262144;
    int n = j & 255, k = j >> 8;
    float v = (n < 128) ? Qf[k * 128 + n] : Kf[k * 128 + (n - 128)];
    QKcT[n * 128 + k] = f2bf(v);
  } else if (i < 425984) {             // WoT[1024][128]
    int j = i - 294912;
    int n = j & 1023, k = j >> 10;
    WoT[(size_t)n * 128 + k] = f2bf(W_o[(size_t)k * 1024 + n]);
  } else if (i < 426240) {             // bcat[256]
    int j = i - 425984;
    bcat[j] = (j < 128) ? b_in[j] : b_v[j - 128];
  }
}

// ---------------------------------------------------------------------------
// GEMM1 (fused x-convert): x fp32 [8192x1024] @ WcatT -> XP | V,VT.
// BM=64 BN=128 BK=128. A: global->reg->bf16->swizzled ds_write (T14 split);
// B: gll16 pre-swizzled. Counted vmcnt(8), 2 barriers/iter, never drain 0.
// ---------------------------------------------------------------------------
__global__ __launch_bounds__(256) void gemm_xw(
    const float* __restrict__ x, const ushort* __restrict__ WcatT,
    const float* __restrict__ bcat, ushort* __restrict__ XP,
    ushort* __restrict__ V, ushort* __restrict__ VT) {
  __shared__ char sm[2][49152];  // [A 16K | B 32K] x2
  const int bid = blockIdx.x;
  const int swz = (bid & 7) * 32 + (bid >> 3);
  const int bm = (swz >> 1) * 64;
  const int bn = (swz & 1) * 128;
  const int tid = threadIdx.x, w = tid >> 6, l = tid & 63;
  const int wr = w >> 1, wc = w & 1, lr = l & 15, lk = l >> 4;

  const int arow = tid & 63;
  const int acol = (tid >> 6) * 32;  // float index in K-tile
  const float* Ax = x + (size_t)(bm + arow) * DD + acol;
  const ushort* Bg = WcatT + (size_t)bn * DD;

  float4 ra[8];
  f32x4 z = {0.f, 0.f, 0.f, 0.f};
  f32x4 acc[2][4];
#pragma unroll
  for (int m = 0; m < 2; ++m)
#pragma unroll
    for (int n = 0; n < 4; ++n) acc[m][n] = z;

#define LOADA(t)                                                    \
  {                                                                 \
    const float4* p = (const float4*)(Ax + (((t) & 7) << 7));       \
    _Pragma("unroll") for (int j = 0; j < 8; ++j) ra[j] = p[j];     \
  }
#define WRITEA(lds)                                                 \
  {                                                                 \
    _Pragma("unroll") for (int q = 0; q < 4; ++q)                   \
        *(bf16x8*)((lds) + swzoff(arow, acol * 2 + q * 16)) =       \
            pack8(ra[2 * q], ra[2 * q + 1]);                        \
  }

  // prologue: lds[0].A written, [B(0), A(1)] in flight
  LOADA(0);
  stage_swz<8>(Bg, DD, 0, sm[0] + 16384, tid);
  asm volatile("s_waitcnt vmcnt(8)" ::: "memory");  // A(0) regs ready
  WRITEA(sm[0]);
  LOADA(1);

  int cur = 0;
  for (int t = 0; t < 8; ++t) {
    char* nxt = sm[cur ^ 1];
    stage_swz<8>(Bg, DD, ((t + 1) & 7) << 7, nxt + 16384, tid);  // B(t+1)
    asm volatile("s_waitcnt vmcnt(8)" ::: "memory");  // B(t)+A(t+1) done
    WRITEA(nxt);                                      // A(t+1) -> nxt
    LOADA(t + 2);                                     // wrapped, harmless
    asm volatile("s_waitcnt lgkmcnt(0)" ::: "memory");
    __builtin_amdgcn_s_barrier();
    const char* cp = sm[cur];
#pragma unroll
    for (int ks = 0; ks < 4; ++ks) {
      const int kb = ks * 64 + lk * 16;
      bf16x8 af[2], bfp[4];
#pragma unroll
      for (int m = 0; m < 2; ++m) af[m] = ld_swz(cp, wr * 32 + m * 16 + lr, kb);
#pragma unroll
      for (int n = 0; n < 4; ++n)
        bfp[n] = ld_swz(cp + 16384, wc * 64 + n * 16 + lr, kb);
#pragma unroll
      for (int m = 0; m < 2; ++m)
#pragma unroll
        for (int n = 0; n < 4; ++n)
          acc[m][n] = __builtin_amdgcn_mfma_f32_16x16x32_bf16(af[m], bfp[n], acc[m][n], 0, 0, 0);
    }
    __builtin_amdgcn_s_barrier();
    cur ^= 1;
  }
  asm volatile("s_waitcnt vmcnt(0)" ::: "memory");
#undef LOADA
#undef WRITEA

#pragma unroll
  for (int m = 0; m < 2; ++m)
#pragma unroll
    for (int n = 0; n < 4; ++n) {
      const int rowb = bm + wr * 32 + m * 16 + lk * 4;
      const int col = bn + wc * 64 + n * 16 + lr;
      const float bv = bcat[col];
      if (bn == 0) {
#pragma unroll
        for (int j = 0; j < 4; ++j)
          XP[(size_t)(rowb + j) * PP + col] = f2bf(acc[m][n][j] + bv);
      } else {
        const int cc = col - 128;
        ushort4 pk;
#pragma unroll
        for (int j = 0; j < 4; ++j) {
          ushort u = f2bf(acc[m][n][j] + bv);
          V[(size_t)(rowb + j) * PP + cc] = u;
          ((ushort*)&pk)[j] = u;
        }
        *(ushort4*)&VT[(size_t)cc * (BB * TT) + rowb] = pk;
      }
    }
}

// ---------------------------------------------------------------------------
// GEMM2: XP[8192x128] @ QKcat -> Qb | KT,KdT. Single-shot K=128. grid 128.
// ---------------------------------------------------------------------------
__global__ __launch_bounds__(256) void gemm_qk(
    const ushort* __restrict__ XP, const ushort* __restrict__ QKcT,
    const float* __restrict__ decay, ushort* __restrict__ Qb,
    ushort* __restrict__ KT, ushort* __restrict__ KdT) {
  __shared__ char sm[81920];  // A 16K | B 64K
  const int bm = blockIdx.x * 64;
  const int tid = threadIdx.x, w = tid >> 6, l = tid & 63;
  const int lr = l & 15, lk = l >> 4;
  stage_swz<4>(XP + (size_t)bm * PP, PP, 0, sm, tid);
  stage_swz<16>(QKcT, PP, 0, sm + 16384, tid);
  f32x4 z = {0.f, 0.f, 0.f, 0.f};
  f32x4 acc[4][4];
#pragma unroll
  for (int m = 0; m < 4; ++m)
#pragma unroll
    for (int n = 0; n < 4; ++n) acc[m][n] = z;
  __syncthreads();
#pragma unroll
  for (int ks = 0; ks < 4; ++ks) {
    const int kb = ks * 64 + lk * 16;
    bf16x8 af[4], bfp[4];
#pragma unroll
    for (int m = 0; m < 4; ++m) af[m] = ld_swz(sm, m * 16 + lr, kb);
#pragma unroll
    for (int n = 0; n < 4; ++n)
      bfp[n] = ld_swz(sm + 16384, w * 64 + n * 16 + lr, kb);
#pragma unroll
    for (int m = 0; m < 4; ++m)
#pragma unroll
      for (int n = 0; n < 4; ++n)
        acc[m][n] = __builtin_amdgcn_mfma_f32_16x16x32_bf16(af[m], bfp[n], acc[m][n], 0, 0, 0);
  }
#pragma unroll
  for (int m = 0; m < 4; ++m)
#pragma unroll
    for (int n = 0; n < 4; ++n) {
      const int rowb = bm + m * 16 + lk * 4;
      const int col = w * 64 + n * 16 + lr;
      if (col < 128) {
#pragma unroll
        for (int j = 0; j < 4; ++j)
          Qb[(size_t)(rowb + j) * PP + col] = f2bf(acc[m][n][j]);
      } else {
        const int cc = col - 128;
        ushort4 pk, pkd;
#pragma unroll
        for (int j = 0; j < 4; ++j) {
          float v = acc[m][n][j];
          ((ushort*)&pk)[j] = f2bf(v);
          ((ushort*)&pkd)[j] = f2bf(v * decay[(rowb + j) & (TT - 1)]);
        }
        *(ushort4*)&KT[(size_t)cc * (BB * TT) + rowb] = pk;
        *(ushort4*)&KdT[(size_t)cc * (BB * TT) + rowb] = pkd;
      }
    }
}

// ---------------------------------------------------------------------------
// Per-chunk state S^T[j][i] = sum_s Kd[s][j]*V[s][i]  (global-direct MFMA)
// ---------------------------------------------------------------------------
__global__ __launch_bounds__(256) void chunk_state_mfma(
    const ushort* __restrict__ KdT, const ushort* __restrict__ VT,
    float* __restrict__ Sc) {
  const int bc = blockIdx.x, b = bc >> 4, c = bc & 15;
  const size_t s0 = (size_t)b * TT + c * CH;
  const int tid = threadIdx.x, w = tid >> 6, l = tid & 63;
  const int wr = w >> 1, wc = w & 1, lr = l & 15, lk = l >> 4;
  f32x4 z = {0.f, 0.f, 0.f, 0.f};
  f32x4 acc[4][4];
#pragma unroll
  for (int m = 0; m < 4; ++m)
#pragma unroll
    for (int n = 0; n < 4; ++n) acc[m][n] = z;
#pragma unroll
  for (int ks = 0; ks < 4; ++ks) {
    const int kk = ks * 32 + lk * 8;
    bf16x8 af[4], bf[4];
#pragma unroll
    for (int m = 0; m < 4; ++m)
      af[m] = *(const bf16x8*)&KdT[(size_t)(wr * 64 + m * 16 + lr) * 8192 + s0 + kk];
#pragma unroll
    for (int n = 0; n < 4; ++n)
      bf[n] = *(const bf16x8*)&VT[(size_t)(wc * 64 + n * 16 + lr) * 8192 + s0 + kk];
#pragma unroll
    for (int m = 0; m < 4; ++m)
#pragma unroll
      for (int n = 0; n < 4; ++n)
        acc[m][n] = __builtin_amdgcn_mfma_f32_16x16x32_bf16(af[m], bf[n], acc[m][n], 0, 0, 0);
  }
#pragma unroll
  for (int m = 0; m < 4; ++m)
#pragma unroll
    for (int n = 0; n < 4; ++n)
#pragma unroll
      for (int j = 0; j < 4; ++j)
        Sc[(size_t)bc * 16384 + (size_t)(wr * 64 + m * 16 + lk * 4 + j) * 128 +
           (wc * 64 + n * 16 + lr)] = acc[m][n][j];
}

// ---------------------------------------------------------------------------
// Exclusive prefix over chunks -> SxT bf16
// ---------------------------------------------------------------------------
__global__ __launch_bounds__(256) void chunk_scan(const float* __restrict__ Sc,
                                                  ushort* __restrict__ SxT) {
  int b = blockIdx.y;
  int e = blockIdx.x * 256 + threadIdx.x;
  float run = 0.f;
#pragma unroll
  for (int c = 0; c < NC; ++c) {
    size_t idx = ((size_t)(b * NC + c)) * 16384 + e;
    SxT[idx] = f2bf(run);
    run += Sc[idx];
  }
}

// ---------------------------------------------------------------------------
// Attention core, 2 blocks per (b,c): phase1 full 128x128 scores (duplicated),
// phase2 output cols [half*64, half*64+64).  grid 128.
// ---------------------------------------------------------------------------
__global__ __launch_bounds__(256) void attn_mfma(
    const ushort* __restrict__ Qb, const ushort* __restrict__ V,
    const ushort* __restrict__ KT, const ushort* __restrict__ SxT,
    const float* __restrict__ decay, ushort* __restrict__ Y) {
  __shared__ ushort Am[128 * 128];
  const int blk = blockIdx.x;
  const int bc = blk >> 1, half = blk & 1;
  const int b = bc >> 4, c = bc & 15;
  const size_t r0 = (size_t)b * TT + c * CH;
  const int tid = threadIdx.x, w = tid >> 6, l = tid & 63;
  const int wr = w >> 1, wc = w & 1, lr = l & 15, lk = l >> 4;
  const float* dc = decay + c * CH;

  f32x4 z = {0.f, 0.f, 0.f, 0.f};
  f32x4 a1[4][4];
#pragma unroll
  for (int m = 0; m < 4; ++m)
#pragma unroll
    for (int n = 0; n < 4; ++n) a1[m][n] = z;

#pragma unroll
  for (int ks = 0; ks < 4; ++ks) {
    const int kk = ks * 32 + lk * 8;
    bf16x8 af[4], bf[4];
#pragma unroll
    for (int m = 0; m < 4; ++m)
      af[m] = *(const bf16x8*)&Qb[(r0 + wr * 64 + m * 16 + lr) * 128 + kk];
#pragma unroll
    for (int n = 0; n < 4; ++n)
      bf[n] = *(const bf16x8*)&V[(r0 + wc * 64 + n * 16 + lr) * 128 + kk];
#pragma unroll
    for (int m = 0; m < 4; ++m)
#pragma unroll
      for (int n = 0; n < 4; ++n)
        a1[m][n] = __builtin_amdgcn_mfma_f32_16x16x32_bf16(af[m], bf[n], a1[m][n], 0, 0, 0);
  }
#pragma unroll
  for (int m = 0; m < 4; ++m)
#pragma unroll
    for (int n = 0; n < 4; ++n)
#pragma unroll
      for (int j = 0; j < 4; ++j) {
        int t = wr * 64 + m * 16 + lk * 4 + j;
        int s = wc * 64 + n * 16 + lr;
        float v = (s <= t) ? a1[m][n][j] * dc[s] : 0.f;
        int byte = t * 256 + ((s * 2) ^ ((t & 7) << 4));
        *(ushort*)((char*)Am + byte) = f2bf(v);
      }
  __syncthreads();

  // phase 2: rows w*32+m*16 (m<2), cols half*64+n*16 (n<4)
  f32x4 a2[2][4];
#pragma unroll
  for (int m = 0; m < 2; ++m)
#pragma unroll
    for (int n = 0; n < 4; ++n) a2[m][n] = z;
#pragma unroll
  for (int ks = 0; ks < 4; ++ks) {
    const int kk = ks * 32 + lk * 8;
    bf16x8 af[2], bf[4];
#pragma unroll
    for (int m = 0; m < 2; ++m) {
      int t = w * 32 + m * 16 + lr;
      af[m] = *(const bf16x8*)((char*)Am + t * 256 + ((kk * 2) ^ ((t & 7) << 4)));
    }
#pragma unroll
    for (int n = 0; n < 4; ++n)
      bf[n] = *(const bf16x8*)&KT[(size_t)(half * 64 + n * 16 + lr) * 8192 + r0 + kk];
#pragma unroll
    for (int m = 0; m < 2; ++m)
#pragma unroll
      for (int n = 0; n < 4; ++n)
        a2[m][n] = __builtin_amdgcn_mfma_f32_16x16x32_bf16(af[m], bf[n], a2[m][n], 0, 0, 0);
  }
#pragma unroll
  for (int ks = 0; ks < 4; ++ks) {
    const int kk = ks * 32 + lk * 8;
    bf16x8 af[2], bf[4];
#pragma unroll
    for (int m = 0; m < 2; ++m)
      af[m] = *(const bf16x8*)&Qb[(r0 + w * 32 + m * 16 + lr) * 128 + kk];
#pragma unroll
    for (int n = 0; n < 4; ++n)
      bf[n] = *(const bf16x8*)&SxT[(size_t)bc * 16384 +
                                   (size_t)(half * 64 + n * 16 + lr) * 128 + kk];
#pragma unroll
    for (int m = 0; m < 2; ++m)
#pragma unroll
      for (int n = 0; n < 4; ++n)
        a2[m][n] = __builtin_amdgcn_mfma_f32_16x16x32_bf16(af[m], bf[n], a2[m][n], 0, 0, 0);
  }
#pragma unroll
  for (int m = 0; m < 2; ++m)
#pragma unroll
    for (int n = 0; n < 4; ++n)
#pragma unroll
      for (int j = 0; j < 4; ++j) {
        int t = w * 32 + m * 16 + lk * 4 + j;
        int col = half * 64 + n * 16 + lr;
        Y[(r0 + t) * 128 + col] = f2bf(a2[m][n][j]);
      }
}

// ---------------------------------------------------------------------------
// GEMM3: Y[8192x128] @ W_o + b_o -> out fp32. Single-shot K=128. grid 1024.
// ---------------------------------------------------------------------------
__global__ __launch_bounds__(256) void gemm_out(
    const ushort* __restrict__ Y, const ushort* __restrict__ WoT,
    const float* __restrict__ b_o, float* __restrict__ out) {
  __shared__ char sm[49152];  // A 16K | B 32K
  const int bid = blockIdx.x;
  const int swz = (bid & 7) * 128 + (bid >> 3);
  const int bm = (swz >> 3) * 64, bn = (swz & 7) * 128;
  const int tid = threadIdx.x, w = tid >> 6, l = tid & 63;
  const int wr = w >> 1, wc = w & 1, lr = l & 15, lk = l >> 4;
  stage_swz<4>(Y + (size_t)bm * PP, PP, 0, sm, tid);
  stage_swz<8>(WoT + (size_t)bn * PP, PP, 0, sm + 16384, tid);
  f32x4 z = {0.f, 0.f, 0.f, 0.f};
  f32x4 acc[2][4];
#pragma unroll
  for (int m = 0; m < 2; ++m)
#pragma unroll
    for (int n = 0; n < 4; ++n) acc[m][n] = z;
  __syncthreads();
#pragma unroll
  for (int ks = 0; ks < 4; ++ks) {
    const int kb = ks * 64 + lk * 16;
    bf16x8 af[2], bfp[4];
#pragma unroll
    for (int m = 0; m < 2; ++m) af[m] = ld_swz(sm, wr * 32 + m * 16 + lr, kb);
#pragma unroll
    for (int n = 0; n < 4; ++n)
      bfp[n] = ld_swz(sm + 16384, wc * 64 + n * 16 + lr, kb);
#pragma unroll
    for (int m = 0; m < 2; ++m)
#pragma unroll
      for (int n = 0; n < 4; ++n)
        acc[m][n] = __builtin_amdgcn_mfma_f32_16x16x32_bf16(af[m], bfp[n], acc[m][n], 0, 0, 0);
  }
#pragma unroll
  for (int m = 0; m < 2; ++m)
#pragma unroll
    for (int n = 0; n < 4; ++n) {
      const int rowb = bm + wr * 32 + m * 16 + lk * 4;
      const int col = bn + wc * 64 + n * 16 + lr;
      const float bv = b_o[col];
#pragma unroll
      for (int j = 0; j < 4; ++j)
        out[(size_t)(rowb + j) * DD + col] = acc[m][n][j] + bv;
    }
}

// ---------------------------------------------------------------------------
extern "C" void kernel_launch(void* const* d_in, const int* in_sizes, int n_in,
                              void* d_out, int out_size, void* d_ws, size_t ws_size,
                              hipStream_t stream) {
  const float* x = (const float*)d_in[0];
  const float* Qf = (const float*)d_in[1];
  const float* Kf = (const float*)d_in[2];
  const float* W_in = (const float*)d_in[3];
  const float* b_in = (const float*)d_in[4];
  const float* W_v = (const float*)d_in[5];
  const float* b_v = (const float*)d_in[6];
  const float* W_o = (const float*)d_in[7];
  const float* b_o = (const float*)d_in[8];
  const float* decay = (const float*)d_in[9];
  float* out = (float*)d_out;
  char* W = (char*)d_ws;

  ushort* XP    = (ushort*)(W);
  ushort* V     = (ushort*)(W + 2097152);
  ushort* VT    = (ushort*)(W + 4194304);
  ushort* Qb    = (ushort*)(W + 6291456);
  ushort* KT    = (ushort*)(W + 8388608);
  ushort* KdT   = (ushort*)(W + 10485760);
  float*  Sc    = (float*)(W + 12582912);
  ushort* SxT   = (ushort*)(W + 16777216);
  ushort* Yb    = (ushort*)(W + 18874368);
  ushort* WcatT = (ushort*)(W + 20971520);
  ushort* QKcT  = (ushort*)(W + 21495808);
  ushort* WoT   = (ushort*)(W + 21561344);
  float*  bcat  = (float*)(W + 21823488);

  prep_w<<<1665, 256, 0, stream>>>(Qf, Kf, W_in, b_in, W_v, b_v, W_o,
                                   WcatT, QKcT, WoT, bcat);
  gemm_xw<<<256, 256, 0, stream>>>(x, WcatT, bcat, XP, V, VT);
  gemm_qk<<<128, 256, 0, stream>>>(XP, QKcT, decay, Qb, KT, KdT);
  chunk_state_mfma<<<BB * NC, 256, 0, stream>>>(KdT, VT, Sc);
  chunk_scan<<<dim3(64, BB), 256, 0, stream>>>(Sc, SxT);
  attn_mfma<<<2 * BB * NC, 256, 0, stream>>>(Qb, V, KT, SxT, decay, Yb);
  gemm_out<<<1024, 256, 0, stream>>>(Yb, WoT, b_o, out);
}

// Round 5
// 56.347 us; speedup vs baseline: 6.7507x; 1.2223x over previous
//
#include <hip/hip_runtime.h>

// B=4, T=2048, D=1024, P=128
#define BB 4
#define TT 2048
#define DD 1024
#define PP 128
#define NC 16
#define CH 128

typedef __attribute__((ext_vector_type(8))) short bf16x8;
typedef __attribute__((ext_vector_type(4))) float f32x4;

__device__ inline ushort f2bf(float f) {
  unsigned u = __builtin_bit_cast(unsigned, f);
  u = (u + 0x7FFF + ((u >> 16) & 1)) >> 16;  // RNE
  return (ushort)u;
}

__device__ inline void gll16(const void* g, void* l) {
  __builtin_amdgcn_global_load_lds(
      (const __attribute__((address_space(1))) void*)g,
      (__attribute__((address_space(3))) void*)l, 16, 0, 0);
}

// T2 swizzle on [rows][128]bf16 tiles (256B rows): kbyte bits 4..6 ^= row&7.
// gll16 dests stay linear; SOURCE carries the inverse permutation (rule #21).
__device__ inline int swzoff(int row, int kbyte) {
  return row * 256 + (kbyte ^ ((row & 7) << 4));
}

template <int NI, int NT>
__device__ inline void stage_swz(const ushort* __restrict__ g, int ld, int koff,
                                 char* lds, int tid) {
#pragma unroll
  for (int j = 0; j < NI; ++j) {
    int L = j * (NT * 16) + tid * 16;
    int row = L >> 8;
    int off = (L & 255) ^ ((row & 7) << 4);
    gll16(g + (size_t)row * ld + koff + (off >> 1),
          lds + j * (NT * 16) + ((tid & (NT - 64)) << 4));
  }
}

__device__ inline bf16x8 ld_swz(const char* lds, int row, int kbyte) {
  return *(const bf16x8*)(lds + swzoff(row, kbyte));
}

__device__ inline bf16x8 pack8(const float4& a, const float4& b) {
  bf16x8 v;
  v[0] = (short)f2bf(a.x); v[1] = (short)f2bf(a.y);
  v[2] = (short)f2bf(a.z); v[3] = (short)f2bf(a.w);
  v[4] = (short)f2bf(b.x); v[5] = (short)f2bf(b.y);
  v[6] = (short)f2bf(b.z); v[7] = (short)f2bf(b.w);
  return v;
}

// ---------------------------------------------------------------------------
// Weights-only prep: transposed bf16 weights + bias concat.
// ---------------------------------------------------------------------------
__global__ __launch_bounds__(256) void prep_w(
    const float* __restrict__ Qf, const float* __restrict__ Kf,
    const float* __restrict__ W_in, const float* __restrict__ b_in,
    const float* __restrict__ W_v, const float* __restrict__ b_v,
    const float* __restrict__ W_o, ushort* __restrict__ WcatT,
    ushort* __restrict__ QKcT, ushort* __restrict__ WoT,
    float* __restrict__ bcat) {
  int i = blockIdx.x * 256 + threadIdx.x;
  if (i < 262144) {                    // WcatT[256][1024]
    int n = i & 255, k = i >> 8;
    float v = (n < 128) ? W_in[k * 128 + n] : W_v[k * 128 + (n - 128)];
    WcatT[(size_t)n * 1024 + k] = f2bf(v);
  } else if (i < 294912) {             // QKcT[256][128]
    int j = i - 262144;
    int n = j & 255, k = j >> 8;
    float v = (n < 128) ? Qf[k * 128 + n] : Kf[k * 128 + (n - 128)];
    QKcT[n * 128 + k] = f2bf(v);
  } else if (i < 425984) {             // WoT[1024][128]
    int j = i - 294912;
    int n = j & 1023, k = j >> 10;
    WoT[(size_t)n * 128 + k] = f2bf(W_o[(size_t)k * 1024 + n]);
  } else if (i < 426240) {             // bcat[256]
    int j = i - 425984;
    bcat[j] = (j < 128) ? b_in[j] : b_v[j - 128];
  }
}

// ---------------------------------------------------------------------------
// GEMM1 (fused x-convert): x fp32 [8192x1024] @ WcatT -> XP | V,VT.
// BM=64 BN=128 BK=128, 512 threads (8 waves = 2/SIMD), dbuf, counted vmcnt(4).
// ---------------------------------------------------------------------------
__global__ __launch_bounds__(512) void gemm_xw(
    const float* __restrict__ x, const ushort* __restrict__ WcatT,
    const float* __restrict__ bcat, ushort* __restrict__ XP,
    ushort* __restrict__ V, ushort* __restrict__ VT) {
  __shared__ char sm[2][49152];  // [A 16K | B 32K] x2
  const int bid = blockIdx.x;
  const int swz = (bid & 7) * 32 + (bid >> 3);
  const int bm = (swz >> 1) * 64;
  const int bn = (swz & 1) * 128;
  const int tid = threadIdx.x, w = tid >> 6, l = tid & 63;
  const int wr = w >> 2, wc = w & 3, lr = l & 15, lk = l >> 4;

  const int arow = tid >> 3;            // 64 rows, 8 threads/row
  const int acol = (tid & 7) * 16;      // 16 floats per thread
  const float* Ax = x + (size_t)(bm + arow) * DD + acol;
  const ushort* Bg = WcatT + (size_t)bn * DD;

  float4 ra[4];
  f32x4 z = {0.f, 0.f, 0.f, 0.f};
  f32x4 acc[2][2];
#pragma unroll
  for (int m = 0; m < 2; ++m)
#pragma unroll
    for (int n = 0; n < 2; ++n) acc[m][n] = z;

#define LOADA(t)                                                  \
  {                                                               \
    const float4* p = (const float4*)(Ax + (((t) & 7) << 7));     \
    _Pragma("unroll") for (int j = 0; j < 4; ++j) ra[j] = p[j];   \
  }
#define WRITEA(lds)                                               \
  {                                                               \
    *(bf16x8*)((lds) + swzoff(arow, acol * 2)) = pack8(ra[0], ra[1]); \
    *(bf16x8*)((lds) + swzoff(arow, acol * 2 + 16)) = pack8(ra[2], ra[3]); \
  }

  // prologue: [B(0), A(1)] in flight after this
  LOADA(0);
  stage_swz<4, 512>(Bg, DD, 0, sm[0] + 16384, tid);
  asm volatile("s_waitcnt vmcnt(4)" ::: "memory");  // A(0) regs ready
  WRITEA(sm[0]);
  LOADA(1);

  int cur = 0;
  for (int t = 0; t < 8; ++t) {
    char* nxt = sm[cur ^ 1];
    stage_swz<4, 512>(Bg, DD, ((t + 1) & 7) << 7, nxt + 16384, tid);
    asm volatile("s_waitcnt vmcnt(4)" ::: "memory");  // B(t)+A(t+1) done
    WRITEA(nxt);
    LOADA(t + 2);                                     // wrapped, harmless
    asm volatile("s_waitcnt lgkmcnt(0)" ::: "memory");
    __builtin_amdgcn_s_barrier();
    const char* cp = sm[cur];
#pragma unroll
    for (int ks = 0; ks < 4; ++ks) {
      const int kb = ks * 64 + lk * 16;
      bf16x8 af[2], bfp[2];
#pragma unroll
      for (int m = 0; m < 2; ++m) af[m] = ld_swz(cp, wr * 32 + m * 16 + lr, kb);
#pragma unroll
      for (int n = 0; n < 2; ++n)
        bfp[n] = ld_swz(cp + 16384, wc * 32 + n * 16 + lr, kb);
#pragma unroll
      for (int m = 0; m < 2; ++m)
#pragma unroll
        for (int n = 0; n < 2; ++n)
          acc[m][n] = __builtin_amdgcn_mfma_f32_16x16x32_bf16(af[m], bfp[n], acc[m][n], 0, 0, 0);
    }
    __builtin_amdgcn_s_barrier();
    cur ^= 1;
  }
  asm volatile("s_waitcnt vmcnt(0)" ::: "memory");
#undef LOADA
#undef WRITEA

#pragma unroll
  for (int m = 0; m < 2; ++m)
#pragma unroll
    for (int n = 0; n < 2; ++n) {
      const int rowb = bm + wr * 32 + m * 16 + lk * 4;
      const int col = bn + wc * 32 + n * 16 + lr;
      const float bv = bcat[col];
      if (bn == 0) {
#pragma unroll
        for (int j = 0; j < 4; ++j)
          XP[(size_t)(rowb + j) * PP + col] = f2bf(acc[m][n][j] + bv);
      } else {
        const int cc = col - 128;
        ushort4 pk;
#pragma unroll
        for (int j = 0; j < 4; ++j) {
          ushort u = f2bf(acc[m][n][j] + bv);
          V[(size_t)(rowb + j) * PP + cc] = u;
          ((ushort*)&pk)[j] = u;
        }
        *(ushort4*)&VT[(size_t)cc * (BB * TT) + rowb] = pk;
      }
    }
}

// ---------------------------------------------------------------------------
// Fused GEMM2 + chunk-state, one block per (b,c) chunk. 512 threads.
//  a) XP[chunk 128x128] @ QKcat[128x256] -> Qb, KT (global)
//  b) Kd = K*decay -> swizzled LDS tile (never hits global)
//  c) S^T[j][i] = sum_s Kd[s][j]*V[s][i] -> Sc fp32 (global)
// ---------------------------------------------------------------------------
__global__ __launch_bounds__(512) void qk_state(
    const ushort* __restrict__ XP, const ushort* __restrict__ QKcT,
    const ushort* __restrict__ VT, const float* __restrict__ decay,
    ushort* __restrict__ Qb, ushort* __restrict__ KT,
    float* __restrict__ Sc) {
  __shared__ char sm[98304];  // [A 32K | B 64K]; A region reused for KdT
  char* smA = sm;
  char* smB = sm + 32768;
  const int bc = blockIdx.x;
  const size_t r0 = (size_t)(bc >> 4) * TT + (bc & 15) * CH;
  const int tid = threadIdx.x, w = tid >> 6, l = tid & 63;
  const int wr = w >> 2, wc = w & 3, lr = l & 15, lk = l >> 4;

  stage_swz<4, 512>(XP + r0 * PP, PP, 0, smA, tid);
  stage_swz<8, 512>(QKcT, PP, 0, smB, tid);

  f32x4 z = {0.f, 0.f, 0.f, 0.f};
  f32x4 acc[4][4];
#pragma unroll
  for (int m = 0; m < 4; ++m)
#pragma unroll
    for (int n = 0; n < 4; ++n) acc[m][n] = z;
  __syncthreads();  // drains vmcnt+lgkmcnt

#pragma unroll
  for (int ks = 0; ks < 4; ++ks) {
    const int kb = ks * 64 + lk * 16;
    bf16x8 af[4], bfp[4];
#pragma unroll
    for (int m = 0; m < 4; ++m) af[m] = ld_swz(smA, wr * 64 + m * 16 + lr, kb);
#pragma unroll
    for (int n = 0; n < 4; ++n)
      bfp[n] = ld_swz(smB, wc * 64 + n * 16 + lr, kb);
#pragma unroll
    for (int m = 0; m < 4; ++m)
#pragma unroll
      for (int n = 0; n < 4; ++n)
        acc[m][n] = __builtin_amdgcn_mfma_f32_16x16x32_bf16(af[m], bfp[n], acc[m][n], 0, 0, 0);
  }
  __syncthreads();  // A-region reads done everywhere; safe to overwrite

  // epilogue: Q -> global; K -> global + decay-folded KdT tile in LDS (smA)
#pragma unroll
  for (int m = 0; m < 4; ++m)
#pragma unroll
    for (int n = 0; n < 4; ++n) {
      const int rowb = wr * 64 + m * 16 + lk * 4;   // chunk-local row s
      const int col = wc * 64 + n * 16 + lr;
      if (col < 128) {
#pragma unroll
        for (int j = 0; j < 4; ++j)
          Qb[(r0 + rowb + j) * PP + col] = f2bf(acc[m][n][j]);
      } else {
        const int cc = col - 128;
        ushort4 pk;
#pragma unroll
        for (int j = 0; j < 4; ++j) {
          float v = acc[m][n][j];
          ((ushort*)&pk)[j] = f2bf(v);
          ushort kd = f2bf(v * decay[(r0 + rowb + j) & (TT - 1)]);
          *(ushort*)(smA + swzoff(cc, (rowb + j) * 2)) = kd;
        }
        *(ushort4*)&KT[(size_t)cc * (BB * TT) + r0 + rowb] = pk;
      }
    }
  __syncthreads();  // KdT tile complete

  // state GEMM: 128x128, warp grid 2x4 (rows 64, cols 32 per wave)
  f32x4 a2[4][2];
#pragma unroll
  for (int m = 0; m < 4; ++m)
#pragma unroll
    for (int n = 0; n < 2; ++n) a2[m][n] = z;
#pragma unroll
  for (int ks = 0; ks < 4; ++ks) {
    const int kb = ks * 64 + lk * 16, kk = ks * 32 + lk * 8;
    bf16x8 af[4], bfp[2];
#pragma unroll
    for (int m = 0; m < 4; ++m) af[m] = ld_swz(smA, wr * 64 + m * 16 + lr, kb);
#pragma unroll
    for (int n = 0; n < 2; ++n)
      bfp[n] = *(const bf16x8*)&VT[(size_t)(wc * 32 + n * 16 + lr) * (BB * TT) + r0 + kk];
#pragma unroll
    for (int m = 0; m < 4; ++m)
#pragma unroll
      for (int n = 0; n < 2; ++n)
        a2[m][n] = __builtin_amdgcn_mfma_f32_16x16x32_bf16(af[m], bfp[n], a2[m][n], 0, 0, 0);
  }
#pragma unroll
  for (int m = 0; m < 4; ++m)
#pragma unroll
    for (int n = 0; n < 2; ++n)
#pragma unroll
      for (int j = 0; j < 4; ++j)
        Sc[(size_t)bc * 16384 + (size_t)(wr * 64 + m * 16 + lk * 4 + j) * 128 +
           (wc * 32 + n * 16 + lr)] = a2[m][n][j];
}

// ---------------------------------------------------------------------------
// Exclusive prefix over chunks -> SxT bf16
// ---------------------------------------------------------------------------
__global__ __launch_bounds__(256) void chunk_scan(const float* __restrict__ Sc,
                                                  ushort* __restrict__ SxT) {
  int b = blockIdx.y;
  int e = blockIdx.x * 256 + threadIdx.x;
  float run = 0.f;
#pragma unroll
  for (int c = 0; c < NC; ++c) {
    size_t idx = ((size_t)(b * NC + c)) * 16384 + e;
    SxT[idx] = f2bf(run);
    run += Sc[idx];
  }
}

// ---------------------------------------------------------------------------
// Attention core, 4 blocks per (b,c): (row-half hr) x (col-half hc).
// phase1: scores rows [hr*64,+64) x all 128 cols; phase2: Y 64x64 tile.
// grid 256 = full chip.
// ---------------------------------------------------------------------------
__global__ __launch_bounds__(256) void attn_mfma(
    const ushort* __restrict__ Qb, const ushort* __restrict__ V,
    const ushort* __restrict__ KT, const ushort* __restrict__ SxT,
    const float* __restrict__ decay, ushort* __restrict__ Y) {
  __shared__ char Am[64 * 256];  // 16 KB swizzled scores, local rows
  const int blk = blockIdx.x;
  const int bc = blk >> 2, hr = (blk >> 1) & 1, hc = blk & 1;
  const int b = bc >> 4, c = bc & 15;
  const size_t r0 = (size_t)b * TT + c * CH;
  const int tid = threadIdx.x, w = tid >> 6, l = tid & 63;
  const int wr = w >> 1, wc = w & 1, lr = l & 15, lk = l >> 4;
  const float* dc = decay + c * CH;

  f32x4 z = {0.f, 0.f, 0.f, 0.f};
  f32x4 a1[2][4];
#pragma unroll
  for (int m = 0; m < 2; ++m)
#pragma unroll
    for (int n = 0; n < 4; ++n) a1[m][n] = z;

  // phase 1: A[t][s] = Q[t]·V[s], rows hr*64 + wr*32 + m*16
#pragma unroll
  for (int ks = 0; ks < 4; ++ks) {
    const int kk = ks * 32 + lk * 8;
    bf16x8 af[2], bf[4];
#pragma unroll
    for (int m = 0; m < 2; ++m)
      af[m] = *(const bf16x8*)&Qb[(r0 + hr * 64 + wr * 32 + m * 16 + lr) * 128 + kk];
#pragma unroll
    for (int n = 0; n < 4; ++n)
      bf[n] = *(const bf16x8*)&V[(r0 + wc * 64 + n * 16 + lr) * 128 + kk];
#pragma unroll
    for (int m = 0; m < 2; ++m)
#pragma unroll
      for (int n = 0; n < 4; ++n)
        a1[m][n] = __builtin_amdgcn_mfma_f32_16x16x32_bf16(af[m], bf[n], a1[m][n], 0, 0, 0);
  }
#pragma unroll
  for (int m = 0; m < 2; ++m)
#pragma unroll
    for (int n = 0; n < 4; ++n)
#pragma unroll
      for (int j = 0; j < 4; ++j) {
        int tl = wr * 32 + m * 16 + lk * 4 + j;   // local row
        int t = hr * 64 + tl;
        int s = wc * 64 + n * 16 + lr;
        float v = (s <= t) ? a1[m][n][j] * dc[s] : 0.f;
        *(ushort*)(Am + swzoff(tl, s * 2)) = f2bf(v);
      }
  __syncthreads();

  // phase 2: Y[64x64] = Am @ K + Q @ Sx ; warp grid 2x2, wave 32x32
  f32x4 a2[2][2];
#pragma unroll
  for (int m = 0; m < 2; ++m)
#pragma unroll
    for (int n = 0; n < 2; ++n) a2[m][n] = z;
#pragma unroll
  for (int ks = 0; ks < 4; ++ks) {
    const int kb = ks * 64 + lk * 16, kk = ks * 32 + lk * 8;
    bf16x8 af[2], bf[2];
#pragma unroll
    for (int m = 0; m < 2; ++m)
      af[m] = ld_swz(Am, wr * 32 + m * 16 + lr, kb);
#pragma unroll
    for (int n = 0; n < 2; ++n)
      bf[n] = *(const bf16x8*)&KT[(size_t)(hc * 64 + wc * 32 + n * 16 + lr) * (BB * TT) + r0 + kk];
#pragma unroll
    for (int m = 0; m < 2; ++m)
#pragma unroll
      for (int n = 0; n < 2; ++n)
        a2[m][n] = __builtin_amdgcn_mfma_f32_16x16x32_bf16(af[m], bf[n], a2[m][n], 0, 0, 0);
  }
#pragma unroll
  for (int ks = 0; ks < 4; ++ks) {
    const int kk = ks * 32 + lk * 8;
    bf16x8 af[2], bf[2];
#pragma unroll
    for (int m = 0; m < 2; ++m)
      af[m] = *(const bf16x8*)&Qb[(r0 + hr * 64 + wr * 32 + m * 16 + lr) * 128 + kk];
#pragma unroll
    for (int n = 0; n < 2; ++n)
      bf[n] = *(const bf16x8*)&SxT[(size_t)bc * 16384 +
                                   (size_t)(hc * 64 + wc * 32 + n * 16 + lr) * 128 + kk];
#pragma unroll
    for (int m = 0; m < 2; ++m)
#pragma unroll
      for (int n = 0; n < 2; ++n)
        a2[m][n] = __builtin_amdgcn_mfma_f32_16x16x32_bf16(af[m], bf[n], a2[m][n], 0, 0, 0);
  }
#pragma unroll
  for (int m = 0; m < 2; ++m)
#pragma unroll
    for (int n = 0; n < 2; ++n)
#pragma unroll
      for (int j = 0; j < 4; ++j) {
        int t = hr * 64 + wr * 32 + m * 16 + lk * 4 + j;
        int col = hc * 64 + wc * 32 + n * 16 + lr;
        Y[(r0 + t) * 128 + col] = f2bf(a2[m][n][j]);
      }
}

// ---------------------------------------------------------------------------
// GEMM3: Y[8192x128] @ W_o + b_o -> out fp32. Single-shot K=128. grid 1024.
// ---------------------------------------------------------------------------
__global__ __launch_bounds__(256) void gemm_out(
    const ushort* __restrict__ Y, const ushort* __restrict__ WoT,
    const float* __restrict__ b_o, float* __restrict__ out) {
  __shared__ char sm[49152];  // A 16K | B 32K
  const int bid = blockIdx.x;
  const int swz = (bid & 7) * 128 + (bid >> 3);
  const int bm = (swz >> 3) * 64, bn = (swz & 7) * 128;
  const int tid = threadIdx.x, w = tid >> 6, l = tid & 63;
  const int wr = w >> 1, wc = w & 1, lr = l & 15, lk = l >> 4;
  stage_swz<4, 256>(Y + (size_t)bm * PP, PP, 0, sm, tid);
  stage_swz<8, 256>(WoT + (size_t)bn * PP, PP, 0, sm + 16384, tid);
  f32x4 z = {0.f, 0.f, 0.f, 0.f};
  f32x4 acc[2][4];
#pragma unroll
  for (int m = 0; m < 2; ++m)
#pragma unroll
    for (int n = 0; n < 4; ++n) acc[m][n] = z;
  __syncthreads();
#pragma unroll
  for (int ks = 0; ks < 4; ++ks) {
    const int kb = ks * 64 + lk * 16;
    bf16x8 af[2], bfp[4];
#pragma unroll
    for (int m = 0; m < 2; ++m) af[m] = ld_swz(sm, wr * 32 + m * 16 + lr, kb);
#pragma unroll
    for (int n = 0; n < 4; ++n)
      bfp[n] = ld_swz(sm + 16384, wc * 64 + n * 16 + lr, kb);
#pragma unroll
    for (int m = 0; m < 2; ++m)
#pragma unroll
      for (int n = 0; n < 4; ++n)
        acc[m][n] = __builtin_amdgcn_mfma_f32_16x16x32_bf16(af[m], bfp[n], acc[m][n], 0, 0, 0);
  }
#pragma unroll
  for (int m = 0; m < 2; ++m)
#pragma unroll
    for (int n = 0; n < 4; ++n) {
      const int rowb = bm + wr * 32 + m * 16 + lk * 4;
      const int col = bn + wc * 64 + n * 16 + lr;
      const float bv = b_o[col];
#pragma unroll
      for (int j = 0; j < 4; ++j)
        out[(size_t)(rowb + j) * DD + col] = acc[m][n][j] + bv;
    }
}

// ---------------------------------------------------------------------------
extern "C" void kernel_launch(void* const* d_in, const int* in_sizes, int n_in,
                              void* d_out, int out_size, void* d_ws, size_t ws_size,
                              hipStream_t stream) {
  const float* x = (const float*)d_in[0];
  const float* Qf = (const float*)d_in[1];
  const float* Kf = (const float*)d_in[2];
  const float* W_in = (const float*)d_in[3];
  const float* b_in = (const float*)d_in[4];
  const float* W_v = (const float*)d_in[5];
  const float* b_v = (const float*)d_in[6];
  const float* W_o = (const float*)d_in[7];
  const float* b_o = (const float*)d_in[8];
  const float* decay = (const float*)d_in[9];
  float* out = (float*)d_out;
  char* W = (char*)d_ws;

  ushort* XP    = (ushort*)(W);
  ushort* V     = (ushort*)(W + 2097152);
  ushort* VT    = (ushort*)(W + 4194304);
  ushort* Qb    = (ushort*)(W + 6291456);
  ushort* KT    = (ushort*)(W + 8388608);
  float*  Sc    = (float*)(W + 10485760);   // 4 MB
  ushort* SxT   = (ushort*)(W + 14680064);
  ushort* Yb    = (ushort*)(W + 16777216);
  ushort* WcatT = (ushort*)(W + 18874368);
  ushort* QKcT  = (ushort*)(W + 19398656);
  ushort* WoT   = (ushort*)(W + 19464192);
  float*  bcat  = (float*)(W + 19726336);

  prep_w<<<1665, 256, 0, stream>>>(Qf, Kf, W_in, b_in, W_v, b_v, W_o,
                                   WcatT, QKcT, WoT, bcat);
  gemm_xw<<<256, 512, 0, stream>>>(x, WcatT, bcat, XP, V, VT);
  qk_state<<<BB * NC, 512, 0, stream>>>(XP, QKcT, VT, decay, Qb, KT, Sc);
  chunk_scan<<<dim3(64, BB), 256, 0, stream>>>(Sc, SxT);
  attn_mfma<<<4 * BB * NC, 256, 0, stream>>>(Qb, V, KT, SxT, decay, Yb);
  gemm_out<<<1024, 256, 0, stream>>>(Yb, WoT, b_o, out);
}

// Round 6
// 50.990 us; speedup vs baseline: 7.4600x; 1.1051x over previous
//
#include <hip/hip_runtime.h>

// B=4, T=2048, D=1024, P=128
#define BB 4
#define TT 2048
#define DD 1024
#define PP 128
#define NC 16
#define CH 128

typedef __attribute__((ext_vector_type(8))) short bf16x8;
typedef __attribute__((ext_vector_type(4))) float f32x4;

__device__ inline ushort f2bf(float f) {
  unsigned u = __builtin_bit_cast(unsigned, f);
  u = (u + 0x7FFF + ((u >> 16) & 1)) >> 16;  // RNE
  return (ushort)u;
}

__device__ inline void gll16(const void* g, void* l) {
  __builtin_amdgcn_global_load_lds(
      (const __attribute__((address_space(1))) void*)g,
      (__attribute__((address_space(3))) void*)l, 16, 0, 0);
}

// T2 swizzle, 256B rows (128 bf16): kbyte bits 4..6 ^= row&7.
__device__ inline int swzoff(int row, int kbyte) {
  return row * 256 + (kbyte ^ ((row & 7) << 4));
}
// T2 swizzle, 128B rows (64 bf16)
__device__ inline int swz128(int row, int kbyte) {
  return row * 128 + (kbyte ^ ((row & 7) << 4));
}

template <int NI, int NT>
__device__ inline void stage_swz(const ushort* __restrict__ g, int ld, int koff,
                                 char* lds, int tid) {
#pragma unroll
  for (int j = 0; j < NI; ++j) {
    int L = j * (NT * 16) + tid * 16;
    int row = L >> 8;
    int off = (L & 255) ^ ((row & 7) << 4);
    gll16(g + (size_t)row * ld + koff + (off >> 1),
          lds + j * (NT * 16) + ((tid & (NT - 64)) << 4));
  }
}
template <int NI, int NT>
__device__ inline void stage_swz128(const ushort* __restrict__ g, int ld,
                                    int koff, char* lds, int tid) {
#pragma unroll
  for (int j = 0; j < NI; ++j) {
    int L = j * (NT * 16) + tid * 16;
    int row = L >> 7;
    int off = (L & 127) ^ ((row & 7) << 4);
    gll16(g + (size_t)row * ld + koff + (off >> 1),
          lds + j * (NT * 16) + ((tid & (NT - 64)) << 4));
  }
}

__device__ inline bf16x8 ld_swz(const char* lds, int row, int kbyte) {
  return *(const bf16x8*)(lds + swzoff(row, kbyte));
}
__device__ inline bf16x8 ld_swz128(const char* lds, int row, int kbyte) {
  return *(const bf16x8*)(lds + swz128(row, kbyte));
}

__device__ inline bf16x8 pack8(const float4& a, const float4& b) {
  bf16x8 v;
  v[0] = (short)f2bf(a.x); v[1] = (short)f2bf(a.y);
  v[2] = (short)f2bf(a.z); v[3] = (short)f2bf(a.w);
  v[4] = (short)f2bf(b.x); v[5] = (short)f2bf(b.y);
  v[6] = (short)f2bf(b.z); v[7] = (short)f2bf(b.w);
  return v;
}

// ---------------------------------------------------------------------------
// Tiled transpose-convert weight prep: coalesced reads AND writes via LDS.
// 64x64 tiles. grid 105: [0,64) WcatT, [64,96) WoT, [96,104) QKcT, 104 bcat.
// ---------------------------------------------------------------------------
__global__ __launch_bounds__(256) void prep_t(
    const float* __restrict__ Qf, const float* __restrict__ Kf,
    const float* __restrict__ W_in, const float* __restrict__ b_in,
    const float* __restrict__ W_v, const float* __restrict__ b_v,
    const float* __restrict__ W_o, ushort* __restrict__ WcatT,
    ushort* __restrict__ QKcT, ushort* __restrict__ WoT,
    float* __restrict__ bcat) {
  const int bid = blockIdx.x;
  const int t = threadIdx.x;
  if (bid == 104) {
    bcat[t] = (t < 128) ? b_in[t] : b_v[t - 128];
    return;
  }
  const float* src;
  ushort* dst;
  int ld_src, ld_dst, nn0;
  if (bid < 64) {                  // WcatT[256][1024] from W_in/W_v [1024][128]
    int tn = bid >> 4, tk = bid & 15;
    src = (tn < 2) ? W_in : W_v;
    nn0 = (tn & 1) * 64;
    ld_src = 128;
    src += (size_t)(tk * 64) * 128;
    dst = WcatT + (size_t)(tn * 64) * 1024 + tk * 64;
    ld_dst = 1024;
  } else if (bid < 96) {           // WoT[1024][128] from W_o [128][1024]
    int j = bid - 64, tn = j >> 1, tk = j & 1;
    src = W_o;
    nn0 = tn * 64;
    ld_src = 1024;
    src += (size_t)(tk * 64) * 1024;
    dst = WoT + (size_t)(tn * 64) * 128 + tk * 64;
    ld_dst = 128;
  } else {                         // QKcT[256][128] from Qf/Kf [128][128]
    int j = bid - 96, tn = j >> 1, tk = j & 1;
    src = (tn < 2) ? Qf : Kf;
    nn0 = (tn & 1) * 64;
    ld_src = 128;
    src += (size_t)(tk * 64) * 128;
    dst = QKcT + (size_t)(tn * 64) * 128 + tk * 64;
    ld_dst = 128;
  }
  __shared__ ushort Tt[64][68];
  const int kr = t >> 4, nc = (t & 15) * 4;
#pragma unroll
  for (int p = 0; p < 4; ++p) {
    float4 v = *(const float4*)&src[(size_t)(p * 16 + kr) * ld_src + nn0 + nc];
    Tt[p * 16 + kr][nc + 0] = f2bf(v.x);
    Tt[p * 16 + kr][nc + 1] = f2bf(v.y);
    Tt[p * 16 + kr][nc + 2] = f2bf(v.z);
    Tt[p * 16 + kr][nc + 3] = f2bf(v.w);
  }
  __syncthreads();
  const int nr = t >> 4, kc = (t & 15) * 4;
#pragma unroll
  for (int p = 0; p < 4; ++p) {
    ushort4 o;
    o.x = Tt[kc + 0][p * 16 + nr];
    o.y = Tt[kc + 1][p * 16 + nr];
    o.z = Tt[kc + 2][p * 16 + nr];
    o.w = Tt[kc + 3][p * 16 + nr];
    *(ushort4*)&dst[(size_t)(p * 16 + nr) * ld_dst + kc] = o;
  }
}

// ---------------------------------------------------------------------------
// GEMM1 (fused x-convert): x fp32 [8192x1024] @ WcatT -> XP | V,VT.
// BM=64 BN=128 BK=64, 512 threads, 48KB LDS dbuf (2-3 blocks/CU), vmcnt(2).
// VT written via LDS-transpose epilogue (coalesced).
// ---------------------------------------------------------------------------
__global__ __launch_bounds__(512, 4) void gemm_xw(
    const float* __restrict__ x, const ushort* __restrict__ WcatT,
    const float* __restrict__ bcat, ushort* __restrict__ XP,
    ushort* __restrict__ V, ushort* __restrict__ VT) {
  __shared__ char sm[2][24576];  // [A 8K | B 16K] x2
  const int bid = blockIdx.x;
  const int swz = (bid & 7) * 32 + (bid >> 3);
  const int bm = (swz >> 1) * 64;
  const int bn = (swz & 1) * 128;
  const int tid = threadIdx.x, w = tid >> 6, l = tid & 63;
  const int wr = w >> 2, wc = w & 3, lr = l & 15, lk = l >> 4;

  const int arow = tid >> 3;       // 64 rows, 8 thr/row
  const int acol = (tid & 7) * 8;  // 8 floats per thread
  const float* Ax = x + (size_t)(bm + arow) * DD + acol;
  const ushort* Bg = WcatT + (size_t)bn * DD;

  float4 ra[2];
  f32x4 z = {0.f, 0.f, 0.f, 0.f};
  f32x4 acc[2][2];
#pragma unroll
  for (int m = 0; m < 2; ++m)
#pragma unroll
    for (int n = 0; n < 2; ++n) acc[m][n] = z;

#define LOADA(t)                                                 \
  {                                                              \
    const float4* p = (const float4*)(Ax + (((t) & 15) << 6));   \
    ra[0] = p[0];                                                \
    ra[1] = p[1];                                                \
  }
#define WRITEA(lds) \
  { *(bf16x8*)((lds) + swz128(arow, acol * 2)) = pack8(ra[0], ra[1]); }

  LOADA(0);
  stage_swz128<2, 512>(Bg, DD, 0, sm[0] + 8192, tid);
  asm volatile("s_waitcnt vmcnt(2)" ::: "memory");  // A(0) regs ready
  WRITEA(sm[0]);
  LOADA(1);

  int cur = 0;
  for (int t = 0; t < 16; ++t) {
    char* nxt = sm[cur ^ 1];
    stage_swz128<2, 512>(Bg, DD, ((t + 1) & 15) << 6, nxt + 8192, tid);
    asm volatile("s_waitcnt vmcnt(2)" ::: "memory");  // B(t)+A(t+1) done
    WRITEA(nxt);
    LOADA(t + 2);  // wrapped, harmless
    asm volatile("s_waitcnt lgkmcnt(0)" ::: "memory");
    __builtin_amdgcn_s_barrier();
    const char* cp = sm[cur];
#pragma unroll
    for (int ks = 0; ks < 2; ++ks) {
      const int kb = ks * 64 + lk * 16;
      bf16x8 af[2], bfp[2];
#pragma unroll
      for (int m = 0; m < 2; ++m)
        af[m] = ld_swz128(cp, wr * 32 + m * 16 + lr, kb);
#pragma unroll
      for (int n = 0; n < 2; ++n)
        bfp[n] = ld_swz128(cp + 8192, wc * 32 + n * 16 + lr, kb);
#pragma unroll
      for (int m = 0; m < 2; ++m)
#pragma unroll
        for (int n = 0; n < 2; ++n)
          acc[m][n] = __builtin_amdgcn_mfma_f32_16x16x32_bf16(af[m], bfp[n], acc[m][n], 0, 0, 0);
    }
    __builtin_amdgcn_s_barrier();
    cur ^= 1;
  }
  asm volatile("s_waitcnt vmcnt(0)" ::: "memory");
#undef LOADA
#undef WRITEA

  if (bn == 0) {
#pragma unroll
    for (int m = 0; m < 2; ++m)
#pragma unroll
      for (int n = 0; n < 2; ++n) {
        const int rowb = bm + wr * 32 + m * 16 + lk * 4;
        const int col = wc * 32 + n * 16 + lr;
        const float bv = bcat[col];
#pragma unroll
        for (int j = 0; j < 4; ++j)
          XP[(size_t)(rowb + j) * PP + col] = f2bf(acc[m][n][j] + bv);
      }
  } else {
    ushort(*VTt)[72] = (ushort(*)[72]) & sm[0][0];  // 128x72 ushort = 18KB
#pragma unroll
    for (int m = 0; m < 2; ++m)
#pragma unroll
      for (int n = 0; n < 2; ++n) {
        const int tl = wr * 32 + m * 16 + lk * 4;  // local time 0..63
        const int cc = wc * 32 + n * 16 + lr;      // feature 0..127
        const float bv = bcat[128 + cc];
#pragma unroll
        for (int j = 0; j < 4; ++j) {
          ushort u = f2bf(acc[m][n][j] + bv);
          V[(size_t)(bm + tl + j) * PP + cc] = u;
          VTt[cc][tl + j] = u;
        }
      }
    __syncthreads();
    const int row = tid >> 2;  // feature 0..127
#pragma unroll
    for (int i = 0; i < 2; ++i) {
      const int ch = (tid & 3) * 2 + i;  // 8-time chunk 0..7
      bf16x8 v = *(const bf16x8*)&VTt[row][ch * 8];
      *(bf16x8*)&VT[(size_t)row * (BB * TT) + bm + ch * 8] = v;
    }
  }
}

// ---------------------------------------------------------------------------
// Fused QK-proj + half-chunk state, one block per (chunk, M-half). 128 blocks.
//  a) XP[64x128] @ QKcat[128x256] -> Qb ; Kd=K*decay -> swizzled LDS
//  b) KdT global dump (coalesced, from LDS)
//  c) S_half^T[j][i] = sum_{s in half} Kd[s][j]*V[s][i] -> Sc2 fp32
// ---------------------------------------------------------------------------
__global__ __launch_bounds__(512, 4) void qk_state(
    const ushort* __restrict__ XP, const ushort* __restrict__ QKcT,
    const ushort* __restrict__ VT, const float* __restrict__ decay,
    ushort* __restrict__ Qb, ushort* __restrict__ KdT,
    float* __restrict__ Sc2) {
  __shared__ char sm[81920];  // [A/Kd 16K | B 64K]
  char* smA = sm;
  char* smB = sm + 16384;
  const int blk = blockIdx.x;
  const int bc = blk >> 1, mh = blk & 1;
  const size_t r0 = (size_t)(bc >> 4) * TT + (bc & 15) * CH;
  const size_t rh = r0 + mh * 64;
  const int tid = threadIdx.x, w = tid >> 6, l = tid & 63;
  const int wr = w >> 2, wc = w & 3, lr = l & 15, lk = l >> 4;

  stage_swz<2, 512>(XP + rh * PP, PP, 0, smA, tid);   // 64 x 256B
  stage_swz<8, 512>(QKcT, PP, 0, smB, tid);           // 256 x 256B

  f32x4 z = {0.f, 0.f, 0.f, 0.f};
  f32x4 acc[2][4];
#pragma unroll
  for (int m = 0; m < 2; ++m)
#pragma unroll
    for (int n = 0; n < 4; ++n) acc[m][n] = z;
  __syncthreads();

#pragma unroll
  for (int ks = 0; ks < 4; ++ks) {
    const int kb = ks * 64 + lk * 16;
    bf16x8 af[2], bfp[4];
#pragma unroll
    for (int m = 0; m < 2; ++m) af[m] = ld_swz(smA, wr * 32 + m * 16 + lr, kb);
#pragma unroll
    for (int n = 0; n < 4; ++n)
      bfp[n] = ld_swz(smB, wc * 64 + n * 16 + lr, kb);
#pragma unroll
    for (int m = 0; m < 2; ++m)
#pragma unroll
      for (int n = 0; n < 4; ++n)
        acc[m][n] = __builtin_amdgcn_mfma_f32_16x16x32_bf16(af[m], bfp[n], acc[m][n], 0, 0, 0);
  }
  __syncthreads();  // smA reads done; region reusable for Kd tile

#pragma unroll
  for (int m = 0; m < 2; ++m)
#pragma unroll
    for (int n = 0; n < 4; ++n) {
      const int rowl = wr * 32 + m * 16 + lk * 4;  // local time 0..63
      const int col = wc * 64 + n * 16 + lr;
      if (col < 128) {
#pragma unroll
        for (int j = 0; j < 4; ++j)
          Qb[(rh + rowl + j) * PP + col] = f2bf(acc[m][n][j]);
      } else {
        const int cc = col - 128;
#pragma unroll
        for (int j = 0; j < 4; ++j) {
          float v = acc[m][n][j] * decay[(rh + rowl + j) & (TT - 1)];
          *(ushort*)(smA + swz128(cc, (rowl + j) * 2)) = f2bf(v);
        }
      }
    }
  __syncthreads();  // Kd tile complete

  // KdT global dump: rows = feature (128), 64 times, coalesced 16B/lane
  {
    const int cc = tid >> 2;
#pragma unroll
    for (int i = 0; i < 2; ++i) {
      const int ch = (tid & 3) * 2 + i;
      bf16x8 v = ld_swz128(smA, cc, ch * 16);
      *(bf16x8*)&KdT[(size_t)cc * (BB * TT) + rh + ch * 8] = v;
    }
  }

  // state half-GEMM: M=128 (feature j), N=128 (feature i), K=64 (times)
  f32x4 a2[4][2];
#pragma unroll
  for (int m = 0; m < 4; ++m)
#pragma unroll
    for (int n = 0; n < 2; ++n) a2[m][n] = z;
#pragma unroll
  for (int ks = 0; ks < 2; ++ks) {
    const int kb = ks * 64 + lk * 16;
    const int kk = ks * 32 + lk * 8;
    bf16x8 af[4], bfp[2];
#pragma unroll
    for (int m = 0; m < 4; ++m)
      af[m] = ld_swz128(smA, wr * 64 + m * 16 + lr, kb);
#pragma unroll
    for (int n = 0; n < 2; ++n)
      bfp[n] = *(const bf16x8*)&VT[(size_t)(wc * 32 + n * 16 + lr) * (BB * TT) + rh + kk];
#pragma unroll
    for (int m = 0; m < 4; ++m)
#pragma unroll
      for (int n = 0; n < 2; ++n)
        a2[m][n] = __builtin_amdgcn_mfma_f32_16x16x32_bf16(af[m], bfp[n], a2[m][n], 0, 0, 0);
  }
#pragma unroll
  for (int m = 0; m < 4; ++m)
#pragma unroll
    for (int n = 0; n < 2; ++n)
#pragma unroll
      for (int j = 0; j < 4; ++j)
        Sc2[((size_t)bc * 2 + mh) * 16384 +
            (size_t)(wr * 64 + m * 16 + lk * 4 + j) * 128 +
            (wc * 32 + n * 16 + lr)] = a2[m][n][j];
}

// ---------------------------------------------------------------------------
// Exclusive prefix over chunks (summing the 2 M-half partial states) -> SxT
// ---------------------------------------------------------------------------
__global__ __launch_bounds__(256) void chunk_scan(const float* __restrict__ Sc2,
                                                  ushort* __restrict__ SxT) {
  const int b = blockIdx.y;
  const int e = blockIdx.x * 256 + threadIdx.x;
  float run = 0.f;
#pragma unroll
  for (int c = 0; c < NC; ++c) {
    const size_t bc = (size_t)(b * NC + c);
    SxT[bc * 16384 + e] = f2bf(run);
    run += Sc2[bc * 2 * 16384 + e] + Sc2[(bc * 2 + 1) * 16384 + e];
  }
}

// ---------------------------------------------------------------------------
// Attention core, 4 blocks per (b,c): (row-half hr) x (col-half hc). grid 256.
// Y = tril(Q V^T) Kd + Q Sx   (decay folded into Kd and Sx)
// ---------------------------------------------------------------------------
__global__ __launch_bounds__(256) void attn_mfma(
    const ushort* __restrict__ Qb, const ushort* __restrict__ V,
    const ushort* __restrict__ KdT, const ushort* __restrict__ SxT,
    ushort* __restrict__ Y) {
  __shared__ char Am[64 * 256];  // 16 KB swizzled scores, local rows
  const int blk = blockIdx.x;
  const int bc = blk >> 2, hr = (blk >> 1) & 1, hc = blk & 1;
  const int b = bc >> 4, c = bc & 15;
  const size_t r0 = (size_t)b * TT + c * CH;
  const int tid = threadIdx.x, w = tid >> 6, l = tid & 63;
  const int wr = w >> 1, wc = w & 1, lr = l & 15, lk = l >> 4;

  f32x4 z = {0.f, 0.f, 0.f, 0.f};
  f32x4 a1[2][4];
#pragma unroll
  for (int m = 0; m < 2; ++m)
#pragma unroll
    for (int n = 0; n < 4; ++n) a1[m][n] = z;

  // phase 1: raw scores A[t][s] = Q[t]·V[s], rows hr*64 + wr*32 + m*16
#pragma unroll
  for (int ks = 0; ks < 4; ++ks) {
    const int kk = ks * 32 + lk * 8;
    bf16x8 af[2], bf[4];
#pragma unroll
    for (int m = 0; m < 2; ++m)
      af[m] = *(const bf16x8*)&Qb[(r0 + hr * 64 + wr * 32 + m * 16 + lr) * 128 + kk];
#pragma unroll
    for (int n = 0; n < 4; ++n)
      bf[n] = *(const bf16x8*)&V[(r0 + wc * 64 + n * 16 + lr) * 128 + kk];
#pragma unroll
    for (int m = 0; m < 2; ++m)
#pragma unroll
      for (int n = 0; n < 4; ++n)
        a1[m][n] = __builtin_amdgcn_mfma_f32_16x16x32_bf16(af[m], bf[n], a1[m][n], 0, 0, 0);
  }
#pragma unroll
  for (int m = 0; m < 2; ++m)
#pragma unroll
    for (int n = 0; n < 4; ++n)
#pragma unroll
      for (int j = 0; j < 4; ++j) {
        int tl = wr * 32 + m * 16 + lk * 4 + j;  // local row
        int t = hr * 64 + tl;
        int s = wc * 64 + n * 16 + lr;
        float v = (s <= t) ? a1[m][n][j] : 0.f;
        *(ushort*)(Am + swzoff(tl, s * 2)) = f2bf(v);
      }
  __syncthreads();

  // phase 2: Y[64x64] = Am @ Kd + Q @ Sx ; warp grid 2x2, wave 32x32
  f32x4 a2[2][2];
#pragma unroll
  for (int m = 0; m < 2; ++m)
#pragma unroll
    for (int n = 0; n < 2; ++n) a2[m][n] = z;
#pragma unroll
  for (int ks = 0; ks < 4; ++ks) {
    const int kb = ks * 64 + lk * 16, kk = ks * 32 + lk * 8;
    bf16x8 af[2], bf[2];
#pragma unroll
    for (int m = 0; m < 2; ++m)
      af[m] = ld_swz(Am, wr * 32 + m * 16 + lr, kb);
#pragma unroll
    for (int n = 0; n < 2; ++n)
      bf[n] = *(const bf16x8*)&KdT[(size_t)(hc * 64 + wc * 32 + n * 16 + lr) * (BB * TT) + r0 + kk];
#pragma unroll
    for (int m = 0; m < 2; ++m)
#pragma unroll
      for (int n = 0; n < 2; ++n)
        a2[m][n] = __builtin_amdgcn_mfma_f32_16x16x32_bf16(af[m], bf[n], a2[m][n], 0, 0, 0);
  }
#pragma unroll
  for (int ks = 0; ks < 4; ++ks) {
    const int kk = ks * 32 + lk * 8;
    bf16x8 af[2], bf[2];
#pragma unroll
    for (int m = 0; m < 2; ++m)
      af[m] = *(const bf16x8*)&Qb[(r0 + hr * 64 + wr * 32 + m * 16 + lr) * 128 + kk];
#pragma unroll
    for (int n = 0; n < 2; ++n)
      bf[n] = *(const bf16x8*)&SxT[(size_t)bc * 16384 +
                                   (size_t)(hc * 64 + wc * 32 + n * 16 + lr) * 128 + kk];
#pragma unroll
    for (int m = 0; m < 2; ++m)
#pragma unroll
      for (int n = 0; n < 2; ++n)
        a2[m][n] = __builtin_amdgcn_mfma_f32_16x16x32_bf16(af[m], bf[n], a2[m][n], 0, 0, 0);
  }
#pragma unroll
  for (int m = 0; m < 2; ++m)
#pragma unroll
    for (int n = 0; n < 2; ++n)
#pragma unroll
      for (int j = 0; j < 4; ++j) {
        int t = hr * 64 + wr * 32 + m * 16 + lk * 4 + j;
        int col = hc * 64 + wc * 32 + n * 16 + lr;
        Y[(r0 + t) * 128 + col] = f2bf(a2[m][n][j]);
      }
}

// ---------------------------------------------------------------------------
// GEMM3: Y[8192x128] @ W_o + b_o -> out fp32. Single-shot K=128. grid 1024.
// ---------------------------------------------------------------------------
__global__ __launch_bounds__(256) void gemm_out(
    const ushort* __restrict__ Y, const ushort* __restrict__ WoT,
    const float* __restrict__ b_o, float* __restrict__ out) {
  __shared__ char sm[49152];  // A 16K | B 32K
  const int bid = blockIdx.x;
  const int swz = (bid & 7) * 128 + (bid >> 3);
  const int bm = (swz >> 3) * 64, bn = (swz & 7) * 128;
  const int tid = threadIdx.x, w = tid >> 6, l = tid & 63;
  const int wr = w >> 1, wc = w & 1, lr = l & 15, lk = l >> 4;
  stage_swz<4, 256>(Y + (size_t)bm * PP, PP, 0, sm, tid);
  stage_swz<8, 256>(WoT + (size_t)bn * PP, PP, 0, sm + 16384, tid);
  f32x4 z = {0.f, 0.f, 0.f, 0.f};
  f32x4 acc[2][4];
#pragma unroll
  for (int m = 0; m < 2; ++m)
#pragma unroll
    for (int n = 0; n < 4; ++n) acc[m][n] = z;
  __syncthreads();
#pragma unroll
  for (int ks = 0; ks < 4; ++ks) {
    const int kb = ks * 64 + lk * 16;
    bf16x8 af[2], bfp[4];
#pragma unroll
    for (int m = 0; m < 2; ++m) af[m] = ld_swz(sm, wr * 32 + m * 16 + lr, kb);
#pragma unroll
    for (int n = 0; n < 4; ++n)
      bfp[n] = ld_swz(sm + 16384, wc * 64 + n * 16 + lr, kb);
#pragma unroll
    for (int m = 0; m < 2; ++m)
#pragma unroll
      for (int n = 0; n < 4; ++n)
        acc[m][n] = __builtin_amdgcn_mfma_f32_16x16x32_bf16(af[m], bfp[n], acc[m][n], 0, 0, 0);
  }
#pragma unroll
  for (int m = 0; m < 2; ++m)
#pragma unroll
    for (int n = 0; n < 4; ++n) {
      const int rowb = bm + wr * 32 + m * 16 + lk * 4;
      const int col = bn + wc * 64 + n * 16 + lr;
      const float bv = b_o[col];
#pragma unroll
      for (int j = 0; j < 4; ++j)
        out[(size_t)(rowb + j) * DD + col] = acc[m][n][j] + bv;
    }
}

// ---------------------------------------------------------------------------
extern "C" void kernel_launch(void* const* d_in, const int* in_sizes, int n_in,
                              void* d_out, int out_size, void* d_ws, size_t ws_size,
                              hipStream_t stream) {
  const float* x = (const float*)d_in[0];
  const float* Qf = (const float*)d_in[1];
  const float* Kf = (const float*)d_in[2];
  const float* W_in = (const float*)d_in[3];
  const float* b_in = (const float*)d_in[4];
  const float* W_v = (const float*)d_in[5];
  const float* b_v = (const float*)d_in[6];
  const float* W_o = (const float*)d_in[7];
  const float* b_o = (const float*)d_in[8];
  const float* decay = (const float*)d_in[9];
  float* out = (float*)d_out;
  char* W = (char*)d_ws;

  ushort* XP    = (ushort*)(W);                  // 2 MB
  ushort* V     = (ushort*)(W + 2097152);        // 2 MB
  ushort* VT    = (ushort*)(W + 4194304);        // 2 MB
  ushort* Qb    = (ushort*)(W + 6291456);        // 2 MB
  ushort* KdT   = (ushort*)(W + 8388608);        // 2 MB
  float*  Sc2   = (float*)(W + 10485760);        // 8 MB
  ushort* SxT   = (ushort*)(W + 18874368);       // 2 MB
  ushort* Yb    = (ushort*)(W + 20971520);       // 2 MB
  ushort* WcatT = (ushort*)(W + 23068672);       // 512 KB
  ushort* QKcT  = (ushort*)(W + 23592960);       // 64 KB
  ushort* WoT   = (ushort*)(W + 23658496);       // 256 KB
  float*  bcat  = (float*)(W + 23920640);        // 1 KB

  prep_t<<<105, 256, 0, stream>>>(Qf, Kf, W_in, b_in, W_v, b_v, W_o,
                                  WcatT, QKcT, WoT, bcat);
  gemm_xw<<<256, 512, 0, stream>>>(x, WcatT, bcat, XP, V, VT);
  qk_state<<<2 * BB * NC, 512, 0, stream>>>(XP, QKcT, VT, decay, Qb, KdT, Sc2);
  chunk_scan<<<dim3(64, BB), 256, 0, stream>>>(Sc2, SxT);
  attn_mfma<<<4 * BB * NC, 256, 0, stream>>>(Qb, V, KdT, SxT, Yb);
  gemm_out<<<1024, 256, 0, stream>>>(Yb, WoT, b_o, out);
}